// Round 6
// baseline (732.134 us; speedup 1.0000x reference)
//
#include <hip/hip_runtime.h>
#include <math.h>

// DisplacementTensors: per-edge radial-MLP + segment-sum to nodes + per-node linear map.
// N_NODES=50000, N_EDGES=1600000, DIM_A=DIM_V=32, R0=5, LEAK=0.1
//
// Round 6: round 5's launch_bounds(256,4) made the allocator target 64 VGPR
// and spill ~700MB/dispatch of scratch (WRITE_SIZE 93->443MB). Revert to the
// round-4 codegen (LDS weights, (256,2), natural VGPR=112) and get the
// occupancy instead by shrinking LDS: the rad transpose buffer is halved to
// [4][32][36] and the segmented reduce runs in two 32-slot passes (all 64
// lanes still run the MLP; xb waits in registers for its pass). LDS
// 53.7KB -> 35KB -> 4 blocks/CU at VGPR<=128. CSR build slimmed: no rank
// array (hist counts only; scatter claims slots via atomic cursor on a
// scan copy).
//
// d_out layout: A_a [50000*32] floats, then out_v [50000*32*3] floats.
// ws layout: counts[NN] | offsets[NN+1] | edge_ids[NE]  (6.8 MB)

#define NN 50000
#define NE 1600000
#define DA 32
#define PI_R0 0.62831853071795864769f  // pi / 5

__device__ __forceinline__ void wsync() {
    // intra-wave LDS handoff: wave is lockstep; drain the DS queue so
    // cross-lane reads see this wave's writes.
    asm volatile("s_waitcnt lgkmcnt(0)" ::: "memory");
}

// ---------------- CSR build ----------------

__global__ __launch_bounds__(256) void k_hist(const int* __restrict__ src,
                                              int* __restrict__ counts) {
    const int e = blockIdx.x * 256 + threadIdx.x;   // grid exactly NE/256
    atomicAdd(&counts[src[e]], 1);
}

__global__ __launch_bounds__(256) void k_scan(const int* __restrict__ counts,
                                              int* __restrict__ offsets,
                                              int* __restrict__ cursor) {
    __shared__ int part[256];
    const int CH = (NN + 255) / 256;   // 196
    const int t = threadIdx.x;
    const int base = t * CH;
    int s = 0;
    for (int k = 0; k < CH; ++k) { const int idx = base + k; if (idx < NN) s += counts[idx]; }
    part[t] = s;
    __syncthreads();
    if (t == 0) {
        int run = 0;
        for (int k = 0; k < 256; ++k) { const int v = part[k]; part[k] = run; run += v; }
    }
    __syncthreads();
    int run = part[t];
    for (int k = 0; k < CH; ++k) {
        const int idx = base + k;
        if (idx < NN) { offsets[idx] = run; cursor[idx] = run; run += counts[idx]; }
    }
    if (t == 255) offsets[NN] = run;   // total == NE
}

__global__ __launch_bounds__(256) void k_scatter(const int* __restrict__ src,
                                                 int* __restrict__ cursor,
                                                 int* __restrict__ edge_ids) {
    const int e = blockIdx.x * 256 + threadIdx.x;
    edge_ids[atomicAdd(&cursor[src[e]], 1)] = e;
}

// ---------------- phase A: per-lane MLP over CSR windows + segmented flush ----------------
// block = 256 = 4 waves; wave handles 64 consecutive CSR slots (edges sorted
// by src). Per-lane MLP with uniform-broadcast LDS weight reads (12 DS
// instr/edge, no intra-MLP round-trips). Then a two-pass wave-local
// transpose through a 32-slot padded LDS buffer + serial segmented reduce
// (node id wave-uniform per slot), atomic flush per node-segment.

__global__ __launch_bounds__(256, 2) void dt_window(
    const float* __restrict__ r_ij,
    const float* __restrict__ res_emb,
    const int*   __restrict__ src,
    const int*   __restrict__ dst,
    const int*   __restrict__ edge_ids,
    const float* __restrict__ W1, const float* __restrict__ b1,
    const float* __restrict__ W2, const float* __restrict__ b2,
    const float* __restrict__ W3,
    float* __restrict__ A_a,    // [NN][32]  (accumulates, pre-zeroed)
    float* __restrict__ out_v)  // [NN][32][3] (accumulates raw A_v, pre-zeroed)
{
    __shared__ float sW1[DA*DA], sW2[DA*DA], sW3[DA*DA];   // row-major
    __shared__ float sb1[DA], sb2[DA];
    __shared__ float  rad_lds[4][32][36];   // [wave][halfslot][dim]; pad 36 -> 2-way max on b128 (free)
    __shared__ float4 rvn_lds[4][64];       // [wave][slot] = (vx, vy, vz, bits(node))

    for (int t = threadIdx.x; t < DA*DA; t += 256) {
        sW1[t] = W1[t]; sW2[t] = W2[t]; sW3[t] = W3[t];
    }
    if (threadIdx.x < DA) { sb1[threadIdx.x] = b1[threadIdx.x]; sb2[threadIdx.x] = b2[threadIdx.x]; }
    __syncthreads();

    const int tid  = threadIdx.x;
    const int wv   = tid >> 6;
    const int lane = tid & 63;
    const int slot = blockIdx.x * 256 + tid;   // grid exactly NE/256

    const int eid  = edge_ids[slot];
    const int node = src[eid];

    const float rx = r_ij[eid*3 + 0];
    const float ry = r_ij[eid*3 + 1];
    const float rz = r_ij[eid*3 + 2];
    const float dist = sqrtf(rx*rx + ry*ry + rz*rz);

    // radial encode: coeffs 1+(k>>1) -> only 8 distinct phases
    float xa[DA], xb[DA];
    #pragma unroll
    for (int m = 0; m < 8; ++m) {
        float sph, cph;
        __sincosf(PI_R0 * (float)(m + 1) * dist, &sph, &cph);
        xa[2*m]      = cph;  xa[2*m + 1]      = cph;
        xa[16 + 2*m] = sph;  xa[16 + 2*m + 1] = sph;
    }
    // gather res_emb[dst] (random 128B row, mostly L2-resident)
    const float4* er = (const float4*)(res_emb + (size_t)dst[eid] * DA);
    #pragma unroll
    for (int q = 0; q < 8; ++q) {
        const float4 v = er[q];
        xa[q*4+0] += v.x; xa[q*4+1] += v.y; xa[q*4+2] += v.z; xa[q*4+3] += v.w;
    }

    // layer 1: xb = leaky(W1 xa + b1)   (uniform-address b128 weight broadcasts)
    #pragma unroll
    for (int i = 0; i < DA; ++i) {
        float acc = sb1[i];
        #pragma unroll
        for (int j4 = 0; j4 < 8; ++j4) {
            const float4 w = *(const float4*)&sW1[i*DA + j4*4];
            acc += w.x*xa[j4*4+0] + w.y*xa[j4*4+1] + w.z*xa[j4*4+2] + w.w*xa[j4*4+3];
        }
        xb[i] = (acc >= 0.0f) ? acc : 0.1f * acc;
    }
    // layer 2: xa = leaky(W2 xb + b2)
    #pragma unroll
    for (int i = 0; i < DA; ++i) {
        float acc = sb2[i];
        #pragma unroll
        for (int j4 = 0; j4 < 8; ++j4) {
            const float4 w = *(const float4*)&sW2[i*DA + j4*4];
            acc += w.x*xb[j4*4+0] + w.y*xb[j4*4+1] + w.z*xb[j4*4+2] + w.w*xb[j4*4+3];
        }
        xa[i] = (acc >= 0.0f) ? acc : 0.1f * acc;
    }
    // layer 3: xb = W3 xa
    #pragma unroll
    for (int i = 0; i < DA; ++i) {
        float acc = 0.0f;
        #pragma unroll
        for (int j4 = 0; j4 < 8; ++j4) {
            const float4 w = *(const float4*)&sW3[i*DA + j4*4];
            acc += w.x*xa[j4*4+0] + w.y*xa[j4*4+1] + w.z*xa[j4*4+2] + w.w*xa[j4*4+3];
        }
        xb[i] = acc;
    }

    // equivariant gate: rv = q * tanh(|q|)/|q|, q = r * (7/5)
    const float qx = rx*1.4f, qy = ry*1.4f, qz = rz*1.4f;
    const float nq = sqrtf(qx*qx + qy*qy + qz*qz);
    const float e2 = __expf(2.0f * nq);
    const float sc = (nq > 0.0f)
        ? (e2 - 1.0f) * __builtin_amdgcn_rcpf((e2 + 1.0f) * nq)
        : 0.0f;

    rvn_lds[wv][lane] = make_float4(qx*sc, qy*sc, qz*sc, __int_as_float(node));

    // ---- two-pass transpose + serial segmented reduce ----
    // lane = (p<<5)|i; every lane accumulates all 4 sums for dim i;
    // at flush p=0 writes {A_a, v0}, p=1 writes {v1, v2}.
    const int p = lane >> 5;
    const int i = lane & 31;

    // pass 1: lanes 0..31 stash their rad rows
    if (lane < 32) {
        float* rrow = rad_lds[wv][lane];
        #pragma unroll
        for (int q = 0; q < 8; ++q) {
            *(float4*)&rrow[q*4] = make_float4(xb[q*4+0], xb[q*4+1], xb[q*4+2], xb[q*4+3]);
        }
    }
    wsync();

    float accA = 0.0f, a0 = 0.0f, a1 = 0.0f, a2 = 0.0f;
    int cur = __float_as_int(rvn_lds[wv][0].w);

    #pragma unroll 4
    for (int l = 0; l < 32; ++l) {
        const float4 rvn = rvn_lds[wv][l];          // uniform b128 broadcast
        const int nd = __float_as_int(rvn.w);       // wave-uniform
        const float rd = rad_lds[wv][l][i];         // 32 consecutive banks, 2-way p-broadcast
        if (nd != cur) {                            // wave-uniform branch
            if (p == 0) {
                atomicAdd(&A_a[cur*DA + i], accA);
                atomicAdd(&out_v[(cur*DA + i)*3 + 0], a0);
            } else {
                atomicAdd(&out_v[(cur*DA + i)*3 + 1], a1);
                atomicAdd(&out_v[(cur*DA + i)*3 + 2], a2);
            }
            accA = a0 = a1 = a2 = 0.0f;
            cur = nd;
        }
        accA += rd;
        a0 += rd * rvn.x;
        a1 += rd * rvn.y;
        a2 += rd * rvn.z;
    }
    wsync();   // pass-1 reads retired before rows are overwritten

    // pass 2: lanes 32..63 stash their rad rows into the same 32 rows
    if (lane >= 32) {
        float* rrow = rad_lds[wv][lane - 32];
        #pragma unroll
        for (int q = 0; q < 8; ++q) {
            *(float4*)&rrow[q*4] = make_float4(xb[q*4+0], xb[q*4+1], xb[q*4+2], xb[q*4+3]);
        }
    }
    wsync();

    #pragma unroll 4
    for (int l = 32; l < 64; ++l) {
        const float4 rvn = rvn_lds[wv][l];
        const int nd = __float_as_int(rvn.w);
        const float rd = rad_lds[wv][l - 32][i];
        if (nd != cur) {
            if (p == 0) {
                atomicAdd(&A_a[cur*DA + i], accA);
                atomicAdd(&out_v[(cur*DA + i)*3 + 0], a0);
            } else {
                atomicAdd(&out_v[(cur*DA + i)*3 + 1], a1);
                atomicAdd(&out_v[(cur*DA + i)*3 + 2], a2);
            }
            accA = a0 = a1 = a2 = 0.0f;
            cur = nd;
        }
        accA += rd;
        a0 += rd * rvn.x;
        a1 += rd * rvn.y;
        a2 += rd * rvn.z;
    }
    if (p == 0) {
        atomicAdd(&A_a[cur*DA + i], accA);
        atomicAdd(&out_v[(cur*DA + i)*3 + 0], a0);
    } else {
        atomicAdd(&out_v[(cur*DA + i)*3 + 1], a1);
        atomicAdd(&out_v[(cur*DA + i)*3 + 2], a2);
    }
}

// ---------------- phase B: out_v[n][v][d] = sum_a Wv[v][a] * A_v[n][a][d], in place ----------------

__global__ __launch_bounds__(256) void dt_node(
    const float* __restrict__ Wv,
    float* Av_out)   // aliased read+write, deliberately NOT restrict
{
    __shared__ float sWv[DA*DA];
    for (int i = threadIdx.x; i < DA*DA; i += 256) sWv[i] = Wv[i];
    __syncthreads();

    const int t = blockIdx.x * 256 + threadIdx.x;   // grid exactly NN*32/256
    const int n = t >> 5;
    const int v = t & 31;

    const float* av = Av_out + (size_t)n * (DA*3);
    float o0 = 0.0f, o1 = 0.0f, o2 = 0.0f;
    #pragma unroll
    for (int a = 0; a < DA; ++a) {
        const float w = sWv[v*DA + a];
        o0 += w * av[a*3 + 0];
        o1 += w * av[a*3 + 1];
        o2 += w * av[a*3 + 2];
    }
    __syncthreads();   // all loads of this block's nodes complete before any store
    float* o = Av_out + (size_t)n * (DA*3) + v*3;
    o[0] = o0; o[1] = o1; o[2] = o2;
}

// ---------------- fallback path (atomic version, used only if ws too small) ----------------

__global__ __launch_bounds__(256) void dt_edge_atomic(
    const float* __restrict__ r_ij, const float* __restrict__ res_emb,
    const int* __restrict__ src, const int* __restrict__ dst,
    const float* __restrict__ W1, const float* __restrict__ b1,
    const float* __restrict__ W2, const float* __restrict__ b2,
    const float* __restrict__ W3,
    float* __restrict__ A_a, float* __restrict__ A_v)
{
    __shared__ float sW1[DA*DA], sW2[DA*DA], sW3[DA*DA], sb1[DA], sb2[DA];
    for (int i = threadIdx.x; i < DA*DA; i += 256) { sW1[i]=W1[i]; sW2[i]=W2[i]; sW3[i]=W3[i]; }
    if (threadIdx.x < DA) { sb1[threadIdx.x]=b1[threadIdx.x]; sb2[threadIdx.x]=b2[threadIdx.x]; }
    __syncthreads();
    const int e = blockIdx.x * 256 + threadIdx.x;
    const float rx = r_ij[(size_t)e*3+0], ry = r_ij[(size_t)e*3+1], rz = r_ij[(size_t)e*3+2];
    const float dist = sqrtf(rx*rx + ry*ry + rz*rz);
    float xa[DA], xb[DA];
    #pragma unroll
    for (int m = 0; m < 8; ++m) {
        float sph, cph; __sincosf(PI_R0 * (float)(m + 1) * dist, &sph, &cph);
        xa[2*m] = cph; xa[2*m+1] = cph; xa[16+2*m] = sph; xa[16+2*m+1] = sph;
    }
    const int d = dst[e];
    const float4* er = (const float4*)(res_emb + (size_t)d * DA);
    #pragma unroll
    for (int q = 0; q < 8; ++q) {
        const float4 v = er[q];
        xa[q*4+0]+=v.x; xa[q*4+1]+=v.y; xa[q*4+2]+=v.z; xa[q*4+3]+=v.w;
    }
    #pragma unroll
    for (int i = 0; i < DA; ++i) {
        float acc = sb1[i];
        #pragma unroll
        for (int j = 0; j < DA; ++j) acc += xa[j] * sW1[i*DA+j];
        xb[i] = (acc >= 0.0f) ? acc : 0.1f*acc;
    }
    #pragma unroll
    for (int i = 0; i < DA; ++i) {
        float acc = sb2[i];
        #pragma unroll
        for (int j = 0; j < DA; ++j) acc += xb[j] * sW2[i*DA+j];
        xa[i] = (acc >= 0.0f) ? acc : 0.1f*acc;
    }
    #pragma unroll
    for (int i = 0; i < DA; ++i) {
        float acc = 0.0f;
        #pragma unroll
        for (int j = 0; j < DA; ++j) acc += xa[j] * sW3[i*DA+j];
        xb[i] = acc;
    }
    const float qx = rx*1.4f, qy = ry*1.4f, qz = rz*1.4f;
    const float nq = sqrtf(qx*qx+qy*qy+qz*qz);
    const float sc = (nq > 0.0f) ? (tanhf(nq)/nq) : 0.0f;
    const float vx = qx*sc, vy = qy*sc, vz = qz*sc;
    const int s = src[e];
    float* pa = A_a + (size_t)s * DA;
    float* pv = A_v + (size_t)s * (DA*3);
    #pragma unroll
    for (int i = 0; i < DA; ++i) atomicAdd(&pa[i], xb[i]);
    #pragma unroll
    for (int i = 0; i < DA; ++i) {
        atomicAdd(&pv[i*3+0], xb[i]*vx);
        atomicAdd(&pv[i*3+1], xb[i]*vy);
        atomicAdd(&pv[i*3+2], xb[i]*vz);
    }
}

// ---------------- launch ----------------

extern "C" void kernel_launch(void* const* d_in, const int* in_sizes, int n_in,
                              void* d_out, int out_size, void* d_ws, size_t ws_size,
                              hipStream_t stream) {
    const float* r_ij    = (const float*)d_in[0];
    const float* res_emb = (const float*)d_in[1];
    const int*   src     = (const int*)d_in[2];
    const int*   dst     = (const int*)d_in[3];
    const float* W1      = (const float*)d_in[4];
    const float* b1      = (const float*)d_in[5];
    const float* W2      = (const float*)d_in[6];
    const float* b2      = (const float*)d_in[7];
    const float* W3      = (const float*)d_in[8];
    const float* Wv      = (const float*)d_in[9];

    float* A_a   = (float*)d_out;                    // [NN][32]
    float* out_v = (float*)d_out + (size_t)NN * DA;  // [NN][32][3]

    // counts | offsets[NN+1] (kept intact) | cursor[NN] | edge_ids[NE]
    const size_t need = ((size_t)NN + (size_t)(NN + 1) + (size_t)NN + (size_t)NE) * sizeof(int);

    // output is accumulated into -> must be zeroed every call
    hipMemsetAsync(d_out, 0, (size_t)out_size * sizeof(float), stream);

    if (ws_size >= need) {
        int* counts   = (int*)d_ws;
        int* offsets  = counts + NN;
        int* cursor   = offsets + NN + 1;
        int* edge_ids = cursor + NN;

        hipMemsetAsync(counts, 0, (size_t)NN * sizeof(int), stream);
        k_hist   <<<NE / 256, 256, 0, stream>>>(src, counts);
        k_scan   <<<1, 256, 0, stream>>>(counts, offsets, cursor);
        k_scatter<<<NE / 256, 256, 0, stream>>>(src, cursor, edge_ids);
        dt_window<<<NE / 256, 256, 0, stream>>>(r_ij, res_emb, src, dst, edge_ids,
                                                W1, b1, W2, b2, W3, A_a, out_v);
        dt_node  <<<(NN * DA) / 256, 256, 0, stream>>>(Wv, out_v);
    } else {
        dt_edge_atomic<<<NE / 256, 256, 0, stream>>>(r_ij, res_emb, src, dst,
                                                     W1, b1, W2, b2, W3, A_a, out_v);
        dt_node<<<(NN * DA) / 256, 256, 0, stream>>>(Wv, out_v);
    }
}

// Round 7
// 600.070 us; speedup vs baseline: 1.2201x; 1.2201x over previous
//
#include <hip/hip_runtime.h>
#include <math.h>

// DisplacementTensors: per-edge radial-MLP + segment-sum to nodes + per-node linear map.
// N_NODES=50000, N_EDGES=1600000, DIM_A=DIM_V=32, R0=5, LEAK=0.1
//
// Round 7: rounds 4/6 were latency-bound on RANDOM GATHERS in dt_window
// (FETCH 360MB: r_ij ~102MB + dst ~25MB + res_emb 205MB of L2-miss lines),
// which is why occupancy changes had zero effect. Fix:
//  - k_prep (merged into CSR scatter) reads edges SEQUENTIALLY and
//    scatter-WRITES per-slot records {dist, vx,vy,vz bf16, node} + dst
//    (random fire-and-forget writes = bandwidth, not latency).
//  - res_emb converted to packed bf16 (3.2MB -> L2-resident); dt_window's
//    only random gather now hits L2.
//  - dt_window reads records sequentially; MLP/reduce identical to round 6.
//  - CSR build reverted to round-4 hist(rank)/scan/scatter (round 6's
//    cursor scatter cost +150us).
//
// d_out layout: A_a [50000*32] floats, then out_v [50000*32*3] floats.
// ws (new path, 42MB): rec u32[NE*4] | dstm int[NE] | emb16 u32[NN*16] |
//                      counts[NN] | offsets[NN+1] | rank[NE]

#define NN 50000
#define NE 1600000
#define DA 32
#define PI_R0 0.62831853071795864769f  // pi / 5

__device__ __forceinline__ void wsync() {
    // intra-wave LDS handoff: wave is lockstep; drain the DS queue so
    // cross-lane reads see this wave's writes.
    asm volatile("s_waitcnt lgkmcnt(0)" ::: "memory");
}

// round-to-nearest-ish bf16 (add half-ulp then truncate)
__device__ __forceinline__ unsigned bf_hi(float x) {
    return (__float_as_uint(x) + 0x8000u) >> 16;
}
__device__ __forceinline__ unsigned bf_pack2(float lo, float hi) {
    return bf_hi(lo) | ((__float_as_uint(hi) + 0x8000u) & 0xffff0000u);
}

// ---------------- CSR build (round-4 style) ----------------

__global__ __launch_bounds__(256) void k_hist(const int* __restrict__ src,
                                              int* __restrict__ counts,
                                              int* __restrict__ rank) {
    const int e = blockIdx.x * 256 + threadIdx.x;   // grid exactly NE/256
    rank[e] = atomicAdd(&counts[src[e]], 1);
}

__global__ __launch_bounds__(256) void k_scan(const int* __restrict__ counts,
                                              int* __restrict__ offsets) {
    __shared__ int part[256];
    const int CH = (NN + 255) / 256;   // 196
    const int t = threadIdx.x;
    const int base = t * CH;
    int s = 0;
    for (int k = 0; k < CH; ++k) { const int idx = base + k; if (idx < NN) s += counts[idx]; }
    part[t] = s;
    __syncthreads();
    if (t == 0) {
        int run = 0;
        for (int k = 0; k < 256; ++k) { const int v = part[k]; part[k] = run; run += v; }
    }
    __syncthreads();
    int run = part[t];
    for (int k = 0; k < CH; ++k) {
        const int idx = base + k;
        if (idx < NN) { offsets[idx] = run; run += counts[idx]; }
    }
    if (t == 255) offsets[NN] = run;   // total == NE
}

// scatter + per-edge precompute: sequential reads, random fire-and-forget writes
__global__ __launch_bounds__(256) void k_prep(
    const float* __restrict__ r_ij,
    const int*   __restrict__ src,
    const int*   __restrict__ dst,
    const int*   __restrict__ offsets,
    const int*   __restrict__ rank,
    uint4* __restrict__ rec,     // [NE] {dist f32, vx|vy bf16, vz bf16, node}
    int*   __restrict__ dstm)    // [NE]
{
    const int e = blockIdx.x * 256 + threadIdx.x;   // grid exactly NE/256
    const int s = src[e];
    const int slot = offsets[s] + rank[e];

    const float rx = r_ij[(size_t)e*3 + 0];
    const float ry = r_ij[(size_t)e*3 + 1];
    const float rz = r_ij[(size_t)e*3 + 2];
    const float dist = sqrtf(rx*rx + ry*ry + rz*rz);

    // gate: rv = q * tanh(|q|)/|q|, q = r*1.4, |q| = 1.4*dist
    const float nq = 1.4f * dist;
    const float e2 = __expf(2.0f * nq);
    const float sc14 = (nq > 0.0f)
        ? 1.4f * (e2 - 1.0f) * __builtin_amdgcn_rcpf((e2 + 1.0f) * nq)
        : 0.0f;
    const float vx = rx * sc14, vy = ry * sc14, vz = rz * sc14;

    uint4 r;
    r.x = __float_as_uint(dist);
    r.y = bf_pack2(vx, vy);
    r.z = bf_hi(vz);
    r.w = (unsigned)s;
    rec[slot]  = r;
    dstm[slot] = dst[e];
}

// res_emb f32 [NN][32] -> packed bf16 u32 [NN][16]
__global__ __launch_bounds__(256) void k_embcvt(const float* __restrict__ emb,
                                                unsigned* __restrict__ emb16) {
    const int t = blockIdx.x * 256 + threadIdx.x;   // grid exactly NN*16/256 = 3125
    const float a = emb[2*t];
    const float b = emb[2*t + 1];
    emb16[t] = bf_pack2(a, b);
}

// ---------------- phase A: per-lane MLP over CSR windows + segmented flush ----------------
// block = 256 = 4 waves; wave handles 64 consecutive CSR slots (edges sorted
// by src). All per-edge data arrives via SEQUENTIAL record reads; the only
// gather is the bf16 res_emb row (L2-resident). MLP with uniform-broadcast
// LDS weight reads; two-pass wave-local transpose + serial segmented reduce
// (node id wave-uniform per slot); atomic flush per node-segment.

__global__ __launch_bounds__(256, 2) void dt_window(
    const uint4*    __restrict__ rec,
    const int*      __restrict__ dstm,
    const unsigned* __restrict__ emb16,
    const float* __restrict__ W1, const float* __restrict__ b1,
    const float* __restrict__ W2, const float* __restrict__ b2,
    const float* __restrict__ W3,
    float* __restrict__ A_a,    // [NN][32]  (accumulates, pre-zeroed)
    float* __restrict__ out_v)  // [NN][32][3] (accumulates raw A_v, pre-zeroed)
{
    __shared__ float sW1[DA*DA], sW2[DA*DA], sW3[DA*DA];   // row-major
    __shared__ float sb1[DA], sb2[DA];
    __shared__ float  rad_lds[4][32][36];   // [wave][halfslot][dim]
    __shared__ float4 rvn_lds[4][64];       // [wave][slot] = (vx, vy, vz, bits(node))

    for (int t = threadIdx.x; t < DA*DA; t += 256) {
        sW1[t] = W1[t]; sW2[t] = W2[t]; sW3[t] = W3[t];
    }
    if (threadIdx.x < DA) { sb1[threadIdx.x] = b1[threadIdx.x]; sb2[threadIdx.x] = b2[threadIdx.x]; }
    __syncthreads();

    const int tid  = threadIdx.x;
    const int wv   = tid >> 6;
    const int lane = tid & 63;
    const int slot = blockIdx.x * 256 + tid;   // grid exactly NE/256

    const uint4 rc = rec[slot];                // sequential b128
    const float dist = __uint_as_float(rc.x);
    const float vx = __uint_as_float(rc.y << 16);
    const float vy = __uint_as_float(rc.y & 0xffff0000u);
    const float vz = __uint_as_float(rc.z << 16);
    const int  node = (int)rc.w;
    const int  dn   = dstm[slot];              // sequential b32

    // radial encode: coeffs 1+(k>>1) -> only 8 distinct phases
    float xa[DA], xb[DA];
    #pragma unroll
    for (int m = 0; m < 8; ++m) {
        float sph, cph;
        __sincosf(PI_R0 * (float)(m + 1) * dist, &sph, &cph);
        xa[2*m]      = cph;  xa[2*m + 1]      = cph;
        xa[16 + 2*m] = sph;  xa[16 + 2*m + 1] = sph;
    }
    // + res_emb[dst] from packed bf16 (L2-resident, 4 x b128)
    const uint4* ep = (const uint4*)(emb16 + (size_t)dn * 16);
    #pragma unroll
    for (int q = 0; q < 4; ++q) {
        const uint4 u = ep[q];
        xa[q*8 + 0] += __uint_as_float(u.x << 16);
        xa[q*8 + 1] += __uint_as_float(u.x & 0xffff0000u);
        xa[q*8 + 2] += __uint_as_float(u.y << 16);
        xa[q*8 + 3] += __uint_as_float(u.y & 0xffff0000u);
        xa[q*8 + 4] += __uint_as_float(u.z << 16);
        xa[q*8 + 5] += __uint_as_float(u.z & 0xffff0000u);
        xa[q*8 + 6] += __uint_as_float(u.w << 16);
        xa[q*8 + 7] += __uint_as_float(u.w & 0xffff0000u);
    }

    // layer 1: xb = leaky(W1 xa + b1)   (uniform-address b128 weight broadcasts)
    #pragma unroll
    for (int i = 0; i < DA; ++i) {
        float acc = sb1[i];
        #pragma unroll
        for (int j4 = 0; j4 < 8; ++j4) {
            const float4 w = *(const float4*)&sW1[i*DA + j4*4];
            acc += w.x*xa[j4*4+0] + w.y*xa[j4*4+1] + w.z*xa[j4*4+2] + w.w*xa[j4*4+3];
        }
        xb[i] = (acc >= 0.0f) ? acc : 0.1f * acc;
    }
    // layer 2: xa = leaky(W2 xb + b2)
    #pragma unroll
    for (int i = 0; i < DA; ++i) {
        float acc = sb2[i];
        #pragma unroll
        for (int j4 = 0; j4 < 8; ++j4) {
            const float4 w = *(const float4*)&sW2[i*DA + j4*4];
            acc += w.x*xb[j4*4+0] + w.y*xb[j4*4+1] + w.z*xb[j4*4+2] + w.w*xb[j4*4+3];
        }
        xa[i] = (acc >= 0.0f) ? acc : 0.1f * acc;
    }
    // layer 3: xb = W3 xa
    #pragma unroll
    for (int i = 0; i < DA; ++i) {
        float acc = 0.0f;
        #pragma unroll
        for (int j4 = 0; j4 < 8; ++j4) {
            const float4 w = *(const float4*)&sW3[i*DA + j4*4];
            acc += w.x*xa[j4*4+0] + w.y*xa[j4*4+1] + w.z*xa[j4*4+2] + w.w*xa[j4*4+3];
        }
        xb[i] = acc;
    }

    rvn_lds[wv][lane] = make_float4(vx, vy, vz, __int_as_float(node));

    // ---- two-pass transpose + serial segmented reduce ----
    const int p = lane >> 5;
    const int i = lane & 31;

    if (lane < 32) {
        float* rrow = rad_lds[wv][lane];
        #pragma unroll
        for (int q = 0; q < 8; ++q) {
            *(float4*)&rrow[q*4] = make_float4(xb[q*4+0], xb[q*4+1], xb[q*4+2], xb[q*4+3]);
        }
    }
    wsync();

    float accA = 0.0f, a0 = 0.0f, a1 = 0.0f, a2 = 0.0f;
    int cur = __float_as_int(rvn_lds[wv][0].w);

    #pragma unroll 4
    for (int l = 0; l < 32; ++l) {
        const float4 rvn = rvn_lds[wv][l];          // uniform b128 broadcast
        const int nd = __float_as_int(rvn.w);       // wave-uniform
        const float rd = rad_lds[wv][l][i];
        if (nd != cur) {                            // wave-uniform branch
            if (p == 0) {
                atomicAdd(&A_a[cur*DA + i], accA);
                atomicAdd(&out_v[(cur*DA + i)*3 + 0], a0);
            } else {
                atomicAdd(&out_v[(cur*DA + i)*3 + 1], a1);
                atomicAdd(&out_v[(cur*DA + i)*3 + 2], a2);
            }
            accA = a0 = a1 = a2 = 0.0f;
            cur = nd;
        }
        accA += rd;
        a0 += rd * rvn.x;
        a1 += rd * rvn.y;
        a2 += rd * rvn.z;
    }
    wsync();   // pass-1 reads retired before rows are overwritten

    if (lane >= 32) {
        float* rrow = rad_lds[wv][lane - 32];
        #pragma unroll
        for (int q = 0; q < 8; ++q) {
            *(float4*)&rrow[q*4] = make_float4(xb[q*4+0], xb[q*4+1], xb[q*4+2], xb[q*4+3]);
        }
    }
    wsync();

    #pragma unroll 4
    for (int l = 32; l < 64; ++l) {
        const float4 rvn = rvn_lds[wv][l];
        const int nd = __float_as_int(rvn.w);
        const float rd = rad_lds[wv][l - 32][i];
        if (nd != cur) {
            if (p == 0) {
                atomicAdd(&A_a[cur*DA + i], accA);
                atomicAdd(&out_v[(cur*DA + i)*3 + 0], a0);
            } else {
                atomicAdd(&out_v[(cur*DA + i)*3 + 1], a1);
                atomicAdd(&out_v[(cur*DA + i)*3 + 2], a2);
            }
            accA = a0 = a1 = a2 = 0.0f;
            cur = nd;
        }
        accA += rd;
        a0 += rd * rvn.x;
        a1 += rd * rvn.y;
        a2 += rd * rvn.z;
    }
    if (p == 0) {
        atomicAdd(&A_a[cur*DA + i], accA);
        atomicAdd(&out_v[(cur*DA + i)*3 + 0], a0);
    } else {
        atomicAdd(&out_v[(cur*DA + i)*3 + 1], a1);
        atomicAdd(&out_v[(cur*DA + i)*3 + 2], a2);
    }
}

// ---------------- phase B: out_v[n][v][d] = sum_a Wv[v][a] * A_v[n][a][d], in place ----------------

__global__ __launch_bounds__(256) void dt_node(
    const float* __restrict__ Wv,
    float* Av_out)   // aliased read+write, deliberately NOT restrict
{
    __shared__ float sWv[DA*DA];
    for (int i = threadIdx.x; i < DA*DA; i += 256) sWv[i] = Wv[i];
    __syncthreads();

    const int t = blockIdx.x * 256 + threadIdx.x;   // grid exactly NN*32/256
    const int n = t >> 5;
    const int v = t & 31;

    const float* av = Av_out + (size_t)n * (DA*3);
    float o0 = 0.0f, o1 = 0.0f, o2 = 0.0f;
    #pragma unroll
    for (int a = 0; a < DA; ++a) {
        const float w = sWv[v*DA + a];
        o0 += w * av[a*3 + 0];
        o1 += w * av[a*3 + 1];
        o2 += w * av[a*3 + 2];
    }
    __syncthreads();   // all loads of this block's nodes complete before any store
    float* o = Av_out + (size_t)n * (DA*3) + v*3;
    o[0] = o0; o[1] = o1; o[2] = o2;
}

// ---------------- legacy path (round-6 window with gathers; used if ws < 42MB) ----------------

__global__ __launch_bounds__(256) void k_scatter_legacy(const int* __restrict__ src,
                                                        const int* __restrict__ offsets,
                                                        const int* __restrict__ rank,
                                                        int* __restrict__ edge_ids) {
    const int e = blockIdx.x * 256 + threadIdx.x;
    edge_ids[offsets[src[e]] + rank[e]] = e;
}

__global__ __launch_bounds__(256, 2) void dt_window_legacy(
    const float* __restrict__ r_ij,
    const float* __restrict__ res_emb,
    const int*   __restrict__ src,
    const int*   __restrict__ dst,
    const int*   __restrict__ edge_ids,
    const float* __restrict__ W1, const float* __restrict__ b1,
    const float* __restrict__ W2, const float* __restrict__ b2,
    const float* __restrict__ W3,
    float* __restrict__ A_a,
    float* __restrict__ out_v)
{
    __shared__ float sW1[DA*DA], sW2[DA*DA], sW3[DA*DA];
    __shared__ float sb1[DA], sb2[DA];
    __shared__ float  rad_lds[4][32][36];
    __shared__ float4 rvn_lds[4][64];

    for (int t = threadIdx.x; t < DA*DA; t += 256) {
        sW1[t] = W1[t]; sW2[t] = W2[t]; sW3[t] = W3[t];
    }
    if (threadIdx.x < DA) { sb1[threadIdx.x] = b1[threadIdx.x]; sb2[threadIdx.x] = b2[threadIdx.x]; }
    __syncthreads();

    const int tid  = threadIdx.x;
    const int wv   = tid >> 6;
    const int lane = tid & 63;
    const int slot = blockIdx.x * 256 + tid;

    const int eid  = edge_ids[slot];
    const int node = src[eid];

    const float rx = r_ij[(size_t)eid*3 + 0];
    const float ry = r_ij[(size_t)eid*3 + 1];
    const float rz = r_ij[(size_t)eid*3 + 2];
    const float dist = sqrtf(rx*rx + ry*ry + rz*rz);

    float xa[DA], xb[DA];
    #pragma unroll
    for (int m = 0; m < 8; ++m) {
        float sph, cph;
        __sincosf(PI_R0 * (float)(m + 1) * dist, &sph, &cph);
        xa[2*m] = cph; xa[2*m+1] = cph;
        xa[16+2*m] = sph; xa[16+2*m+1] = sph;
    }
    const float4* er = (const float4*)(res_emb + (size_t)dst[eid] * DA);
    #pragma unroll
    for (int q = 0; q < 8; ++q) {
        const float4 v = er[q];
        xa[q*4+0] += v.x; xa[q*4+1] += v.y; xa[q*4+2] += v.z; xa[q*4+3] += v.w;
    }
    #pragma unroll
    for (int i = 0; i < DA; ++i) {
        float acc = sb1[i];
        #pragma unroll
        for (int j4 = 0; j4 < 8; ++j4) {
            const float4 w = *(const float4*)&sW1[i*DA + j4*4];
            acc += w.x*xa[j4*4+0] + w.y*xa[j4*4+1] + w.z*xa[j4*4+2] + w.w*xa[j4*4+3];
        }
        xb[i] = (acc >= 0.0f) ? acc : 0.1f * acc;
    }
    #pragma unroll
    for (int i = 0; i < DA; ++i) {
        float acc = sb2[i];
        #pragma unroll
        for (int j4 = 0; j4 < 8; ++j4) {
            const float4 w = *(const float4*)&sW2[i*DA + j4*4];
            acc += w.x*xb[j4*4+0] + w.y*xb[j4*4+1] + w.z*xb[j4*4+2] + w.w*xb[j4*4+3];
        }
        xa[i] = (acc >= 0.0f) ? acc : 0.1f * acc;
    }
    #pragma unroll
    for (int i = 0; i < DA; ++i) {
        float acc = 0.0f;
        #pragma unroll
        for (int j4 = 0; j4 < 8; ++j4) {
            const float4 w = *(const float4*)&sW3[i*DA + j4*4];
            acc += w.x*xa[j4*4+0] + w.y*xa[j4*4+1] + w.z*xa[j4*4+2] + w.w*xa[j4*4+3];
        }
        xb[i] = acc;
    }

    const float qx = rx*1.4f, qy = ry*1.4f, qz = rz*1.4f;
    const float nq = sqrtf(qx*qx + qy*qy + qz*qz);
    const float e2 = __expf(2.0f * nq);
    const float sc = (nq > 0.0f)
        ? (e2 - 1.0f) * __builtin_amdgcn_rcpf((e2 + 1.0f) * nq)
        : 0.0f;

    rvn_lds[wv][lane] = make_float4(qx*sc, qy*sc, qz*sc, __int_as_float(node));

    const int p = lane >> 5;
    const int i = lane & 31;

    if (lane < 32) {
        float* rrow = rad_lds[wv][lane];
        #pragma unroll
        for (int q = 0; q < 8; ++q)
            *(float4*)&rrow[q*4] = make_float4(xb[q*4+0], xb[q*4+1], xb[q*4+2], xb[q*4+3]);
    }
    wsync();

    float accA = 0.0f, a0 = 0.0f, a1 = 0.0f, a2 = 0.0f;
    int cur = __float_as_int(rvn_lds[wv][0].w);

    #pragma unroll 4
    for (int l = 0; l < 32; ++l) {
        const float4 rvn = rvn_lds[wv][l];
        const int nd = __float_as_int(rvn.w);
        const float rd = rad_lds[wv][l][i];
        if (nd != cur) {
            if (p == 0) {
                atomicAdd(&A_a[cur*DA + i], accA);
                atomicAdd(&out_v[(cur*DA + i)*3 + 0], a0);
            } else {
                atomicAdd(&out_v[(cur*DA + i)*3 + 1], a1);
                atomicAdd(&out_v[(cur*DA + i)*3 + 2], a2);
            }
            accA = a0 = a1 = a2 = 0.0f;
            cur = nd;
        }
        accA += rd; a0 += rd*rvn.x; a1 += rd*rvn.y; a2 += rd*rvn.z;
    }
    wsync();
    if (lane >= 32) {
        float* rrow = rad_lds[wv][lane - 32];
        #pragma unroll
        for (int q = 0; q < 8; ++q)
            *(float4*)&rrow[q*4] = make_float4(xb[q*4+0], xb[q*4+1], xb[q*4+2], xb[q*4+3]);
    }
    wsync();
    #pragma unroll 4
    for (int l = 32; l < 64; ++l) {
        const float4 rvn = rvn_lds[wv][l];
        const int nd = __float_as_int(rvn.w);
        const float rd = rad_lds[wv][l - 32][i];
        if (nd != cur) {
            if (p == 0) {
                atomicAdd(&A_a[cur*DA + i], accA);
                atomicAdd(&out_v[(cur*DA + i)*3 + 0], a0);
            } else {
                atomicAdd(&out_v[(cur*DA + i)*3 + 1], a1);
                atomicAdd(&out_v[(cur*DA + i)*3 + 2], a2);
            }
            accA = a0 = a1 = a2 = 0.0f;
            cur = nd;
        }
        accA += rd; a0 += rd*rvn.x; a1 += rd*rvn.y; a2 += rd*rvn.z;
    }
    if (p == 0) {
        atomicAdd(&A_a[cur*DA + i], accA);
        atomicAdd(&out_v[(cur*DA + i)*3 + 0], a0);
    } else {
        atomicAdd(&out_v[(cur*DA + i)*3 + 1], a1);
        atomicAdd(&out_v[(cur*DA + i)*3 + 2], a2);
    }
}

// ---------------- launch ----------------

extern "C" void kernel_launch(void* const* d_in, const int* in_sizes, int n_in,
                              void* d_out, int out_size, void* d_ws, size_t ws_size,
                              hipStream_t stream) {
    const float* r_ij    = (const float*)d_in[0];
    const float* res_emb = (const float*)d_in[1];
    const int*   src     = (const int*)d_in[2];
    const int*   dst     = (const int*)d_in[3];
    const float* W1      = (const float*)d_in[4];
    const float* b1      = (const float*)d_in[5];
    const float* W2      = (const float*)d_in[6];
    const float* b2      = (const float*)d_in[7];
    const float* W3      = (const float*)d_in[8];
    const float* Wv      = (const float*)d_in[9];

    float* A_a   = (float*)d_out;                    // [NN][32]
    float* out_v = (float*)d_out + (size_t)NN * DA;  // [NN][32][3]

    // new-path ws: rec[NE]u32x4 | dstm[NE] | emb16[NN*16] | counts[NN] | offsets[NN+1] | rank[NE]
    const size_t need_new = ((size_t)NE*4 + NE + (size_t)NN*16 + NN + NN + 1 + NE) * sizeof(int);
    // legacy ws: counts | offsets | rank | edge_ids
    const size_t need_leg = ((size_t)NN + NN + 1 + NE + NE) * sizeof(int);

    // output is accumulated into -> must be zeroed every call
    hipMemsetAsync(d_out, 0, (size_t)out_size * sizeof(float), stream);

    if (ws_size >= need_new) {
        uint4*    rec     = (uint4*)d_ws;
        int*      dstm    = (int*)(rec + NE);
        unsigned* emb16   = (unsigned*)(dstm + NE);
        int*      counts  = (int*)(emb16 + (size_t)NN*16);
        int*      offsets = counts + NN;
        int*      rank    = offsets + NN + 1;

        hipMemsetAsync(counts, 0, (size_t)NN * sizeof(int), stream);
        k_hist  <<<NE / 256, 256, 0, stream>>>(src, counts, rank);
        k_scan  <<<1, 256, 0, stream>>>(counts, offsets);
        k_embcvt<<<(NN*16) / 256, 256, 0, stream>>>(res_emb, emb16);
        k_prep  <<<NE / 256, 256, 0, stream>>>(r_ij, src, dst, offsets, rank, rec, dstm);
        dt_window<<<NE / 256, 256, 0, stream>>>(rec, dstm, emb16,
                                                W1, b1, W2, b2, W3, A_a, out_v);
        dt_node <<<(NN * DA) / 256, 256, 0, stream>>>(Wv, out_v);
    } else if (ws_size >= need_leg) {
        int* counts   = (int*)d_ws;
        int* offsets  = counts + NN;
        int* rank     = offsets + NN + 1;
        int* edge_ids = rank + NE;

        hipMemsetAsync(counts, 0, (size_t)NN * sizeof(int), stream);
        k_hist          <<<NE / 256, 256, 0, stream>>>(src, counts, rank);
        k_scan          <<<1, 256, 0, stream>>>(counts, offsets);
        k_scatter_legacy<<<NE / 256, 256, 0, stream>>>(src, offsets, rank, edge_ids);
        dt_window_legacy<<<NE / 256, 256, 0, stream>>>(r_ij, res_emb, src, dst, edge_ids,
                                                       W1, b1, W2, b2, W3, A_a, out_v);
        dt_node         <<<(NN * DA) / 256, 256, 0, stream>>>(Wv, out_v);
    }
}

// Round 8
// 442.262 us; speedup vs baseline: 1.6554x; 1.3568x over previous
//
#include <hip/hip_runtime.h>
#include <math.h>

// DisplacementTensors: per-edge radial-MLP + segment-sum to nodes + per-node linear map.
// N_NODES=50000, N_EDGES=1600000, DIM_A=DIM_V=32, R0=5, LEAK=0.1
//
// Round 8: dt_window has been 390us across THREE different memory structures
// (r4/r6/r7) -> instruction-stream bound. Arithmetic: 768 uniform
// ds_read_b128 weight broadcasts per 64-edge window x ~12cyc x 98 windows/CU
// = 376us: the DS pipe IS the wall. Fix: weights move to the SCALAR path --
// compile-time-constant uniform addresses on __restrict__ kernel args
// scalarize to s_load (constant cache; SGPR operands fold into v_fmac; no DS,
// no VALU). This is round 5's idea minus its fatal (256,4) bound: (256,2)
// keeps natural VGPR ~128 with zero spill (proven r6/r7). LDS staging and
// its __syncthreads are deleted (22.5KB left: transpose buffers only).
//
// d_out layout: A_a [50000*32] floats, then out_v [50000*32*3] floats.
// ws (new path, 42MB): rec u32[NE*4] | dstm int[NE] | emb16 u32[NN*16] |
//                      counts[NN] | offsets[NN+1] | rank[NE]

#define NN 50000
#define NE 1600000
#define DA 32
#define PI_R0 0.62831853071795864769f  // pi / 5

__device__ __forceinline__ void wsync() {
    // intra-wave LDS handoff: wave is lockstep; drain the DS queue so
    // cross-lane reads see this wave's writes.
    asm volatile("s_waitcnt lgkmcnt(0)" ::: "memory");
}

// round-to-nearest-ish bf16 (add half-ulp then truncate)
__device__ __forceinline__ unsigned bf_hi(float x) {
    return (__float_as_uint(x) + 0x8000u) >> 16;
}
__device__ __forceinline__ unsigned bf_pack2(float lo, float hi) {
    return bf_hi(lo) | ((__float_as_uint(hi) + 0x8000u) & 0xffff0000u);
}

// ---------------- CSR build ----------------

__global__ __launch_bounds__(256) void k_hist(const int* __restrict__ src,
                                              int* __restrict__ counts,
                                              int* __restrict__ rank) {
    const int e = blockIdx.x * 256 + threadIdx.x;   // grid exactly NE/256
    rank[e] = atomicAdd(&counts[src[e]], 1);
}

__global__ __launch_bounds__(256) void k_scan(const int* __restrict__ counts,
                                              int* __restrict__ offsets) {
    __shared__ int part[256];
    const int CH = (NN + 255) / 256;   // 196
    const int t = threadIdx.x;
    const int base = t * CH;
    int s = 0;
    for (int k = 0; k < CH; ++k) { const int idx = base + k; if (idx < NN) s += counts[idx]; }
    part[t] = s;
    __syncthreads();
    if (t == 0) {
        int run = 0;
        for (int k = 0; k < 256; ++k) { const int v = part[k]; part[k] = run; run += v; }
    }
    __syncthreads();
    int run = part[t];
    for (int k = 0; k < CH; ++k) {
        const int idx = base + k;
        if (idx < NN) { offsets[idx] = run; run += counts[idx]; }
    }
    if (t == 255) offsets[NN] = run;   // total == NE
}

// scatter + per-edge precompute: sequential reads, random fire-and-forget writes
__global__ __launch_bounds__(256) void k_prep(
    const float* __restrict__ r_ij,
    const int*   __restrict__ src,
    const int*   __restrict__ dst,
    const int*   __restrict__ offsets,
    const int*   __restrict__ rank,
    uint4* __restrict__ rec,     // [NE] {dist f32, vx|vy bf16, vz bf16, node}
    int*   __restrict__ dstm)    // [NE]
{
    const int e = blockIdx.x * 256 + threadIdx.x;   // grid exactly NE/256
    const int s = src[e];
    const int slot = offsets[s] + rank[e];

    const float rx = r_ij[(size_t)e*3 + 0];
    const float ry = r_ij[(size_t)e*3 + 1];
    const float rz = r_ij[(size_t)e*3 + 2];
    const float dist = sqrtf(rx*rx + ry*ry + rz*rz);

    // gate: rv = q * tanh(|q|)/|q|, q = r*1.4, |q| = 1.4*dist
    const float nq = 1.4f * dist;
    const float e2 = __expf(2.0f * nq);
    const float sc14 = (nq > 0.0f)
        ? 1.4f * (e2 - 1.0f) * __builtin_amdgcn_rcpf((e2 + 1.0f) * nq)
        : 0.0f;
    const float vx = rx * sc14, vy = ry * sc14, vz = rz * sc14;

    uint4 r;
    r.x = __float_as_uint(dist);
    r.y = bf_pack2(vx, vy);
    r.z = bf_hi(vz);
    r.w = (unsigned)s;
    rec[slot]  = r;
    dstm[slot] = dst[e];
}

// res_emb f32 [NN][32] -> packed bf16 u32 [NN][16]
__global__ __launch_bounds__(256) void k_embcvt(const float* __restrict__ emb,
                                                unsigned* __restrict__ emb16) {
    const int t = blockIdx.x * 256 + threadIdx.x;   // grid exactly NN*16/256 = 3125
    const float a = emb[2*t];
    const float b = emb[2*t + 1];
    emb16[t] = bf_pack2(a, b);
}

// ---------------- phase A: per-lane MLP over CSR windows + segmented flush ----------------
// block = 256 = 4 waves; wave handles 64 consecutive CSR slots (edges sorted
// by src). Per-edge data via SEQUENTIAL record reads; res_emb gather is bf16
// (L2-resident). MLP weights via SCALAR loads (uniform constant-indexed
// accesses on __restrict__ args -> s_load from constant cache; zero DS ops).
// Two-pass wave-local transpose + serial segmented reduce; atomic flush.

__global__ __launch_bounds__(256, 2) void dt_window(
    const uint4*    __restrict__ rec,
    const int*      __restrict__ dstm,
    const unsigned* __restrict__ emb16,
    const float* __restrict__ W1, const float* __restrict__ b1,
    const float* __restrict__ W2, const float* __restrict__ b2,
    const float* __restrict__ W3,
    float* __restrict__ A_a,    // [NN][32]  (accumulates, pre-zeroed)
    float* __restrict__ out_v)  // [NN][32][3] (accumulates raw A_v, pre-zeroed)
{
    __shared__ float  rad_lds[4][32][36];   // [wave][halfslot][dim]
    __shared__ float4 rvn_lds[4][64];       // [wave][slot] = (vx, vy, vz, bits(node))

    const int tid  = threadIdx.x;
    const int wv   = tid >> 6;
    const int lane = tid & 63;
    const int slot = blockIdx.x * 256 + tid;   // grid exactly NE/256

    const uint4 rc = rec[slot];                // sequential b128
    const float dist = __uint_as_float(rc.x);
    const float vx = __uint_as_float(rc.y << 16);
    const float vy = __uint_as_float(rc.y & 0xffff0000u);
    const float vz = __uint_as_float(rc.z << 16);
    const int  node = (int)rc.w;
    const int  dn   = dstm[slot];              // sequential b32

    // radial encode: coeffs 1+(k>>1) -> only 8 distinct phases
    float xa[DA], xb[DA];
    #pragma unroll
    for (int m = 0; m < 8; ++m) {
        float sph, cph;
        __sincosf(PI_R0 * (float)(m + 1) * dist, &sph, &cph);
        xa[2*m]      = cph;  xa[2*m + 1]      = cph;
        xa[16 + 2*m] = sph;  xa[16 + 2*m + 1] = sph;
    }
    // + res_emb[dst] from packed bf16 (L2-resident, 4 x b128)
    const uint4* ep = (const uint4*)(emb16 + (size_t)dn * 16);
    #pragma unroll
    for (int q = 0; q < 4; ++q) {
        const uint4 u = ep[q];
        xa[q*8 + 0] += __uint_as_float(u.x << 16);
        xa[q*8 + 1] += __uint_as_float(u.x & 0xffff0000u);
        xa[q*8 + 2] += __uint_as_float(u.y << 16);
        xa[q*8 + 3] += __uint_as_float(u.y & 0xffff0000u);
        xa[q*8 + 4] += __uint_as_float(u.z << 16);
        xa[q*8 + 5] += __uint_as_float(u.z & 0xffff0000u);
        xa[q*8 + 6] += __uint_as_float(u.w << 16);
        xa[q*8 + 7] += __uint_as_float(u.w & 0xffff0000u);
    }

    // layer 1: xb = leaky(W1 xa + b1) — constant-indexed uniform loads -> s_load
    #pragma unroll
    for (int i = 0; i < DA; ++i) {
        float acc = b1[i];
        #pragma unroll
        for (int j = 0; j < DA; ++j) acc += W1[i*DA + j] * xa[j];
        xb[i] = (acc >= 0.0f) ? acc : 0.1f * acc;
    }
    // layer 2: xa = leaky(W2 xb + b2)
    #pragma unroll
    for (int i = 0; i < DA; ++i) {
        float acc = b2[i];
        #pragma unroll
        for (int j = 0; j < DA; ++j) acc += W2[i*DA + j] * xb[j];
        xa[i] = (acc >= 0.0f) ? acc : 0.1f * acc;
    }
    // layer 3: xb = W3 xa
    #pragma unroll
    for (int i = 0; i < DA; ++i) {
        float acc = 0.0f;
        #pragma unroll
        for (int j = 0; j < DA; ++j) acc += W3[i*DA + j] * xa[j];
        xb[i] = acc;
    }

    rvn_lds[wv][lane] = make_float4(vx, vy, vz, __int_as_float(node));

    // ---- two-pass transpose + serial segmented reduce ----
    const int p = lane >> 5;
    const int i = lane & 31;

    if (lane < 32) {
        float* rrow = rad_lds[wv][lane];
        #pragma unroll
        for (int q = 0; q < 8; ++q) {
            *(float4*)&rrow[q*4] = make_float4(xb[q*4+0], xb[q*4+1], xb[q*4+2], xb[q*4+3]);
        }
    }
    wsync();

    float accA = 0.0f, a0 = 0.0f, a1 = 0.0f, a2 = 0.0f;
    int cur = __float_as_int(rvn_lds[wv][0].w);

    #pragma unroll 4
    for (int l = 0; l < 32; ++l) {
        const float4 rvn = rvn_lds[wv][l];          // uniform b128 broadcast
        const int nd = __float_as_int(rvn.w);       // wave-uniform
        const float rd = rad_lds[wv][l][i];
        if (nd != cur) {                            // wave-uniform branch
            if (p == 0) {
                atomicAdd(&A_a[cur*DA + i], accA);
                atomicAdd(&out_v[(cur*DA + i)*3 + 0], a0);
            } else {
                atomicAdd(&out_v[(cur*DA + i)*3 + 1], a1);
                atomicAdd(&out_v[(cur*DA + i)*3 + 2], a2);
            }
            accA = a0 = a1 = a2 = 0.0f;
            cur = nd;
        }
        accA += rd;
        a0 += rd * rvn.x;
        a1 += rd * rvn.y;
        a2 += rd * rvn.z;
    }
    wsync();   // pass-1 reads retired before rows are overwritten

    if (lane >= 32) {
        float* rrow = rad_lds[wv][lane - 32];
        #pragma unroll
        for (int q = 0; q < 8; ++q) {
            *(float4*)&rrow[q*4] = make_float4(xb[q*4+0], xb[q*4+1], xb[q*4+2], xb[q*4+3]);
        }
    }
    wsync();

    #pragma unroll 4
    for (int l = 32; l < 64; ++l) {
        const float4 rvn = rvn_lds[wv][l];
        const int nd = __float_as_int(rvn.w);
        const float rd = rad_lds[wv][l - 32][i];
        if (nd != cur) {
            if (p == 0) {
                atomicAdd(&A_a[cur*DA + i], accA);
                atomicAdd(&out_v[(cur*DA + i)*3 + 0], a0);
            } else {
                atomicAdd(&out_v[(cur*DA + i)*3 + 1], a1);
                atomicAdd(&out_v[(cur*DA + i)*3 + 2], a2);
            }
            accA = a0 = a1 = a2 = 0.0f;
            cur = nd;
        }
        accA += rd;
        a0 += rd * rvn.x;
        a1 += rd * rvn.y;
        a2 += rd * rvn.z;
    }
    if (p == 0) {
        atomicAdd(&A_a[cur*DA + i], accA);
        atomicAdd(&out_v[(cur*DA + i)*3 + 0], a0);
    } else {
        atomicAdd(&out_v[(cur*DA + i)*3 + 1], a1);
        atomicAdd(&out_v[(cur*DA + i)*3 + 2], a2);
    }
}

// ---------------- phase B: out_v[n][v][d] = sum_a Wv[v][a] * A_v[n][a][d], in place ----------------

__global__ __launch_bounds__(256) void dt_node(
    const float* __restrict__ Wv,
    float* Av_out)   // aliased read+write, deliberately NOT restrict
{
    __shared__ float sWv[DA*DA];
    for (int i = threadIdx.x; i < DA*DA; i += 256) sWv[i] = Wv[i];
    __syncthreads();

    const int t = blockIdx.x * 256 + threadIdx.x;   // grid exactly NN*32/256
    const int n = t >> 5;
    const int v = t & 31;

    const float* av = Av_out + (size_t)n * (DA*3);
    float o0 = 0.0f, o1 = 0.0f, o2 = 0.0f;
    #pragma unroll
    for (int a = 0; a < DA; ++a) {
        const float w = sWv[v*DA + a];
        o0 += w * av[a*3 + 0];
        o1 += w * av[a*3 + 1];
        o2 += w * av[a*3 + 2];
    }
    __syncthreads();   // all loads of this block's nodes complete before any store
    float* o = Av_out + (size_t)n * (DA*3) + v*3;
    o[0] = o0; o[1] = o1; o[2] = o2;
}

// ---------------- legacy path (used only if ws < 42MB) ----------------

__global__ __launch_bounds__(256) void k_scatter_legacy(const int* __restrict__ src,
                                                        const int* __restrict__ offsets,
                                                        const int* __restrict__ rank,
                                                        int* __restrict__ edge_ids) {
    const int e = blockIdx.x * 256 + threadIdx.x;
    edge_ids[offsets[src[e]] + rank[e]] = e;
}

__global__ __launch_bounds__(256, 2) void dt_window_legacy(
    const float* __restrict__ r_ij,
    const float* __restrict__ res_emb,
    const int*   __restrict__ src,
    const int*   __restrict__ dst,
    const int*   __restrict__ edge_ids,
    const float* __restrict__ W1, const float* __restrict__ b1,
    const float* __restrict__ W2, const float* __restrict__ b2,
    const float* __restrict__ W3,
    float* __restrict__ A_a,
    float* __restrict__ out_v)
{
    __shared__ float  rad_lds[4][32][36];
    __shared__ float4 rvn_lds[4][64];

    const int tid  = threadIdx.x;
    const int wv   = tid >> 6;
    const int lane = tid & 63;
    const int slot = blockIdx.x * 256 + tid;

    const int eid  = edge_ids[slot];
    const int node = src[eid];

    const float rx = r_ij[(size_t)eid*3 + 0];
    const float ry = r_ij[(size_t)eid*3 + 1];
    const float rz = r_ij[(size_t)eid*3 + 2];
    const float dist = sqrtf(rx*rx + ry*ry + rz*rz);

    float xa[DA], xb[DA];
    #pragma unroll
    for (int m = 0; m < 8; ++m) {
        float sph, cph;
        __sincosf(PI_R0 * (float)(m + 1) * dist, &sph, &cph);
        xa[2*m] = cph; xa[2*m+1] = cph;
        xa[16+2*m] = sph; xa[16+2*m+1] = sph;
    }
    const float4* er = (const float4*)(res_emb + (size_t)dst[eid] * DA);
    #pragma unroll
    for (int q = 0; q < 8; ++q) {
        const float4 v = er[q];
        xa[q*4+0] += v.x; xa[q*4+1] += v.y; xa[q*4+2] += v.z; xa[q*4+3] += v.w;
    }
    #pragma unroll
    for (int i = 0; i < DA; ++i) {
        float acc = b1[i];
        #pragma unroll
        for (int j = 0; j < DA; ++j) acc += W1[i*DA + j] * xa[j];
        xb[i] = (acc >= 0.0f) ? acc : 0.1f * acc;
    }
    #pragma unroll
    for (int i = 0; i < DA; ++i) {
        float acc = b2[i];
        #pragma unroll
        for (int j = 0; j < DA; ++j) acc += W2[i*DA + j] * xb[j];
        xa[i] = (acc >= 0.0f) ? acc : 0.1f * acc;
    }
    #pragma unroll
    for (int i = 0; i < DA; ++i) {
        float acc = 0.0f;
        #pragma unroll
        for (int j = 0; j < DA; ++j) acc += W3[i*DA + j] * xa[j];
        xb[i] = acc;
    }

    const float qx = rx*1.4f, qy = ry*1.4f, qz = rz*1.4f;
    const float nq = sqrtf(qx*qx + qy*qy + qz*qz);
    const float e2 = __expf(2.0f * nq);
    const float sc = (nq > 0.0f)
        ? (e2 - 1.0f) * __builtin_amdgcn_rcpf((e2 + 1.0f) * nq)
        : 0.0f;

    rvn_lds[wv][lane] = make_float4(qx*sc, qy*sc, qz*sc, __int_as_float(node));

    const int p = lane >> 5;
    const int i = lane & 31;

    if (lane < 32) {
        float* rrow = rad_lds[wv][lane];
        #pragma unroll
        for (int q = 0; q < 8; ++q)
            *(float4*)&rrow[q*4] = make_float4(xb[q*4+0], xb[q*4+1], xb[q*4+2], xb[q*4+3]);
    }
    wsync();

    float accA = 0.0f, a0 = 0.0f, a1 = 0.0f, a2 = 0.0f;
    int cur = __float_as_int(rvn_lds[wv][0].w);

    #pragma unroll 4
    for (int l = 0; l < 32; ++l) {
        const float4 rvn = rvn_lds[wv][l];
        const int nd = __float_as_int(rvn.w);
        const float rd = rad_lds[wv][l][i];
        if (nd != cur) {
            if (p == 0) {
                atomicAdd(&A_a[cur*DA + i], accA);
                atomicAdd(&out_v[(cur*DA + i)*3 + 0], a0);
            } else {
                atomicAdd(&out_v[(cur*DA + i)*3 + 1], a1);
                atomicAdd(&out_v[(cur*DA + i)*3 + 2], a2);
            }
            accA = a0 = a1 = a2 = 0.0f;
            cur = nd;
        }
        accA += rd; a0 += rd*rvn.x; a1 += rd*rvn.y; a2 += rd*rvn.z;
    }
    wsync();
    if (lane >= 32) {
        float* rrow = rad_lds[wv][lane - 32];
        #pragma unroll
        for (int q = 0; q < 8; ++q)
            *(float4*)&rrow[q*4] = make_float4(xb[q*4+0], xb[q*4+1], xb[q*4+2], xb[q*4+3]);
    }
    wsync();
    #pragma unroll 4
    for (int l = 32; l < 64; ++l) {
        const float4 rvn = rvn_lds[wv][l];
        const int nd = __float_as_int(rvn.w);
        const float rd = rad_lds[wv][l - 32][i];
        if (nd != cur) {
            if (p == 0) {
                atomicAdd(&A_a[cur*DA + i], accA);
                atomicAdd(&out_v[(cur*DA + i)*3 + 0], a0);
            } else {
                atomicAdd(&out_v[(cur*DA + i)*3 + 1], a1);
                atomicAdd(&out_v[(cur*DA + i)*3 + 2], a2);
            }
            accA = a0 = a1 = a2 = 0.0f;
            cur = nd;
        }
        accA += rd; a0 += rd*rvn.x; a1 += rd*rvn.y; a2 += rd*rvn.z;
    }
    if (p == 0) {
        atomicAdd(&A_a[cur*DA + i], accA);
        atomicAdd(&out_v[(cur*DA + i)*3 + 0], a0);
    } else {
        atomicAdd(&out_v[(cur*DA + i)*3 + 1], a1);
        atomicAdd(&out_v[(cur*DA + i)*3 + 2], a2);
    }
}

// ---------------- launch ----------------

extern "C" void kernel_launch(void* const* d_in, const int* in_sizes, int n_in,
                              void* d_out, int out_size, void* d_ws, size_t ws_size,
                              hipStream_t stream) {
    const float* r_ij    = (const float*)d_in[0];
    const float* res_emb = (const float*)d_in[1];
    const int*   src     = (const int*)d_in[2];
    const int*   dst     = (const int*)d_in[3];
    const float* W1      = (const float*)d_in[4];
    const float* b1      = (const float*)d_in[5];
    const float* W2      = (const float*)d_in[6];
    const float* b2      = (const float*)d_in[7];
    const float* W3      = (const float*)d_in[8];
    const float* Wv      = (const float*)d_in[9];

    float* A_a   = (float*)d_out;                    // [NN][32]
    float* out_v = (float*)d_out + (size_t)NN * DA;  // [NN][32][3]

    // new-path ws: rec[NE]u32x4 | dstm[NE] | emb16[NN*16] | counts[NN] | offsets[NN+1] | rank[NE]
    const size_t need_new = ((size_t)NE*4 + NE + (size_t)NN*16 + NN + NN + 1 + NE) * sizeof(int);
    // legacy ws: counts | offsets | rank | edge_ids
    const size_t need_leg = ((size_t)NN + NN + 1 + NE + NE) * sizeof(int);

    // output is accumulated into -> must be zeroed every call
    hipMemsetAsync(d_out, 0, (size_t)out_size * sizeof(float), stream);

    if (ws_size >= need_new) {
        uint4*    rec     = (uint4*)d_ws;
        int*      dstm    = (int*)(rec + NE);
        unsigned* emb16   = (unsigned*)(dstm + NE);
        int*      counts  = (int*)(emb16 + (size_t)NN*16);
        int*      offsets = counts + NN;
        int*      rank    = offsets + NN + 1;

        hipMemsetAsync(counts, 0, (size_t)NN * sizeof(int), stream);
        k_hist  <<<NE / 256, 256, 0, stream>>>(src, counts, rank);
        k_scan  <<<1, 256, 0, stream>>>(counts, offsets);
        k_embcvt<<<(NN*16) / 256, 256, 0, stream>>>(res_emb, emb16);
        k_prep  <<<NE / 256, 256, 0, stream>>>(r_ij, src, dst, offsets, rank, rec, dstm);
        dt_window<<<NE / 256, 256, 0, stream>>>(rec, dstm, emb16,
                                                W1, b1, W2, b2, W3, A_a, out_v);
        dt_node <<<(NN * DA) / 256, 256, 0, stream>>>(Wv, out_v);
    } else if (ws_size >= need_leg) {
        int* counts   = (int*)d_ws;
        int* offsets  = counts + NN;
        int* rank     = offsets + NN + 1;
        int* edge_ids = rank + NE;

        hipMemsetAsync(counts, 0, (size_t)NN * sizeof(int), stream);
        k_hist          <<<NE / 256, 256, 0, stream>>>(src, counts, rank);
        k_scan          <<<1, 256, 0, stream>>>(counts, offsets);
        k_scatter_legacy<<<NE / 256, 256, 0, stream>>>(src, offsets, rank, edge_ids);
        dt_window_legacy<<<NE / 256, 256, 0, stream>>>(r_ij, res_emb, src, dst, edge_ids,
                                                       W1, b1, W2, b2, W3, A_a, out_v);
        dt_node         <<<(NN * DA) / 256, 256, 0, stream>>>(Wv, out_v);
    }
}

// Round 9
// 316.742 us; speedup vs baseline: 2.3115x; 1.3963x over previous
//
#include <hip/hip_runtime.h>
#include <math.h>

// DisplacementTensors: per-edge radial-MLP + segment-sum to nodes + per-node linear map.
// N_NODES=50000, N_EDGES=1600000, DIM_A=DIM_V=32, R0=5, LEAK=0.1
//
// Round 9: round 8 confirmed the DS-wall theory (scalar weights: 390->215us).
// Cycle audit says dt_window burns ~2x the ideal VALU cycles -> compiler is
// emitting s_load -> v_mov -> v_fmac instead of folding the SGPR weight.
// Fix: inline-asm v_pk_fma_f32 (VOP3P packed f32, 2 FMA/instr) with an
// explicit "s" SGPR-pair weight operand. Data is naturally pair-structured
// (radial encode + bf16 emb words are dim-pairs) -> xa/xb become float2
// ext-vectors, zero layout change, bit-identical products.
// Chain: single-block scan -> 3-phase parallel scan; dst packed into rec.w
// (both ids < 65536) deleting the dstm stream.
//
// d_out layout: A_a [50000*32] floats, then out_v [50000*32*3] floats.
// ws (new path, ~36MB): rec u32[NE*4] | emb16 u32[NN*16] | counts[NN] |
//                       offsets[NN+1] | rank[NE] | bsum[256] | bbase[256]

#define NN 50000
#define NE 1600000
#define DA 32
#define PI_R0 0.62831853071795864769f  // pi / 5
#define SCAN_BLOCKS 196                // ceil(NN/256)

typedef float v2f __attribute__((ext_vector_type(2)));

__device__ __forceinline__ void wsync() {
    // intra-wave LDS handoff: wave is lockstep; drain the DS queue so
    // cross-lane reads see this wave's writes.
    asm volatile("s_waitcnt lgkmcnt(0)" ::: "memory");
}

// packed-f32 FMA with weight pair forced onto the scalar path:
// acc.lo += w.lo*x.lo, acc.hi += w.hi*x.hi  (one VOP3P instr, SGPR src0)
__device__ __forceinline__ void pk_fma_s(v2f& acc, v2f w, v2f x) {
    asm("v_pk_fma_f32 %0, %1, %2, %0" : "+v"(acc) : "s"(w), "v"(x));
}

// round-to-nearest-ish bf16 (add half-ulp then truncate)
__device__ __forceinline__ unsigned bf_hi(float x) {
    return (__float_as_uint(x) + 0x8000u) >> 16;
}
__device__ __forceinline__ unsigned bf_pack2(float lo, float hi) {
    return bf_hi(lo) | ((__float_as_uint(hi) + 0x8000u) & 0xffff0000u);
}

// ---------------- CSR build ----------------

__global__ __launch_bounds__(256) void k_hist(const int* __restrict__ src,
                                              int* __restrict__ counts,
                                              int* __restrict__ rank) {
    const int e = blockIdx.x * 256 + threadIdx.x;   // grid exactly NE/256
    rank[e] = atomicAdd(&counts[src[e]], 1);
}

// 3-phase parallel exclusive scan of counts[NN] -> offsets[NN+1]
__global__ __launch_bounds__(256) void k_scanA(const int* __restrict__ counts,
                                               int* __restrict__ bsum) {
    __shared__ int red[256];
    const int t = threadIdx.x;
    const int idx = blockIdx.x * 256 + t;
    red[t] = (idx < NN) ? counts[idx] : 0;
    __syncthreads();
    #pragma unroll
    for (int off = 128; off > 0; off >>= 1) {
        if (t < off) red[t] += red[t + off];
        __syncthreads();
    }
    if (t == 0) bsum[blockIdx.x] = red[0];
}

__global__ __launch_bounds__(256) void k_scanB(const int* __restrict__ bsum,
                                               int* __restrict__ bbase) {
    __shared__ int s[256];
    const int t = threadIdx.x;
    const int v = (t < SCAN_BLOCKS) ? bsum[t] : 0;
    s[t] = v;
    __syncthreads();
    #pragma unroll
    for (int off = 1; off < 256; off <<= 1) {
        const int x = s[t] + ((t >= off) ? s[t - off] : 0);
        __syncthreads();
        s[t] = x;
        __syncthreads();
    }
    if (t < SCAN_BLOCKS) bbase[t] = s[t] - v;   // exclusive
}

__global__ __launch_bounds__(256) void k_scanC(const int* __restrict__ counts,
                                               const int* __restrict__ bbase,
                                               int* __restrict__ offsets) {
    __shared__ int s[256];
    const int t = threadIdx.x;
    const int idx = blockIdx.x * 256 + t;
    const int v = (idx < NN) ? counts[idx] : 0;
    s[t] = v;
    __syncthreads();
    #pragma unroll
    for (int off = 1; off < 256; off <<= 1) {
        const int x = s[t] + ((t >= off) ? s[t - off] : 0);
        __syncthreads();
        s[t] = x;
        __syncthreads();
    }
    const int excl = s[t] - v + bbase[blockIdx.x];
    if (idx < NN) offsets[idx] = excl;
    if (idx == NN - 1) offsets[NN] = excl + v;   // == NE
}

// scatter + per-edge precompute: sequential reads, random fire-and-forget writes.
// rec = {dist f32, vx|vy bf16x2, vz bf16, src u16 | dst u16 << 16}
__global__ __launch_bounds__(256) void k_prep(
    const float* __restrict__ r_ij,
    const int*   __restrict__ src,
    const int*   __restrict__ dst,
    const int*   __restrict__ offsets,
    const int*   __restrict__ rank,
    uint4* __restrict__ rec)
{
    const int e = blockIdx.x * 256 + threadIdx.x;   // grid exactly NE/256
    const int s = src[e];
    const int slot = offsets[s] + rank[e];

    const float rx = r_ij[(size_t)e*3 + 0];
    const float ry = r_ij[(size_t)e*3 + 1];
    const float rz = r_ij[(size_t)e*3 + 2];
    const float dist = sqrtf(rx*rx + ry*ry + rz*rz);

    // gate: rv = q * tanh(|q|)/|q|, q = r*1.4, |q| = 1.4*dist
    const float nq = 1.4f * dist;
    const float e2 = __expf(2.0f * nq);
    const float sc14 = (nq > 0.0f)
        ? 1.4f * (e2 - 1.0f) * __builtin_amdgcn_rcpf((e2 + 1.0f) * nq)
        : 0.0f;
    const float vx = rx * sc14, vy = ry * sc14, vz = rz * sc14;

    uint4 r;
    r.x = __float_as_uint(dist);
    r.y = bf_pack2(vx, vy);
    r.z = bf_hi(vz);
    r.w = (unsigned)s | ((unsigned)dst[e] << 16);   // both < 65536
    rec[slot] = r;
}

// res_emb f32 [NN][32] -> packed bf16 u32 [NN][16]
__global__ __launch_bounds__(256) void k_embcvt(const float* __restrict__ emb,
                                                unsigned* __restrict__ emb16) {
    const int t = blockIdx.x * 256 + threadIdx.x;   // grid exactly NN*16/256 = 3125
    emb16[t] = bf_pack2(emb[2*t], emb[2*t + 1]);
}

// ---------------- phase A: per-lane MLP over CSR windows + segmented flush ----------------
// block = 256 = 4 waves; wave handles 64 consecutive CSR slots. Per-edge data
// via sequential record reads; emb gather is bf16 (L2-resident). MLP in
// packed-f32 (v_pk_fma_f32, SGPR weight pairs). Two-pass wave-local transpose
// + serial segmented reduce; atomic flush per node-segment.

__global__ __launch_bounds__(256, 2) void dt_window(
    const uint4*    __restrict__ rec,
    const unsigned* __restrict__ emb16,
    const float* __restrict__ W1, const float* __restrict__ b1,
    const float* __restrict__ W2, const float* __restrict__ b2,
    const float* __restrict__ W3,
    float* __restrict__ A_a,    // [NN][32]  (accumulates, pre-zeroed)
    float* __restrict__ out_v)  // [NN][32][3] (accumulates raw A_v, pre-zeroed)
{
    __shared__ float  rad_lds[4][32][36];   // [wave][halfslot][dim]
    __shared__ float4 rvn_lds[4][64];       // [wave][slot] = (vx, vy, vz, bits(node))

    const int tid  = threadIdx.x;
    const int wv   = tid >> 6;
    const int lane = tid & 63;
    const int slot = blockIdx.x * 256 + tid;   // grid exactly NE/256

    const uint4 rc = rec[slot];                // sequential b128
    const float dist = __uint_as_float(rc.x);
    const float vx = __uint_as_float(rc.y << 16);
    const float vy = __uint_as_float(rc.y & 0xffff0000u);
    const float vz = __uint_as_float(rc.z << 16);
    const int  node = (int)(rc.w & 0xffffu);
    const int  dn   = (int)(rc.w >> 16);

    const v2f* W1v = (const v2f*)W1;   // [i*16 + j2] = (W[i][2j2], W[i][2j2+1])
    const v2f* W2v = (const v2f*)W2;
    const v2f* W3v = (const v2f*)W3;

    // radial encode: dims come in equal pairs -> v2f lanes directly
    v2f xa[16], xb[16];
    #pragma unroll
    for (int m = 0; m < 8; ++m) {
        float sph, cph;
        __sincosf(PI_R0 * (float)(m + 1) * dist, &sph, &cph);
        xa[m]     = (v2f){cph, cph};
        xa[8 + m] = (v2f){sph, sph};
    }
    // + res_emb[dst] from packed bf16 (one u32 = one dim-pair)
    const uint4* ep = (const uint4*)(emb16 + (size_t)dn * 16);
    #pragma unroll
    for (int q = 0; q < 4; ++q) {
        const uint4 u = ep[q];
        xa[q*4 + 0] += (v2f){__uint_as_float(u.x << 16), __uint_as_float(u.x & 0xffff0000u)};
        xa[q*4 + 1] += (v2f){__uint_as_float(u.y << 16), __uint_as_float(u.y & 0xffff0000u)};
        xa[q*4 + 2] += (v2f){__uint_as_float(u.z << 16), __uint_as_float(u.z & 0xffff0000u)};
        xa[q*4 + 3] += (v2f){__uint_as_float(u.w << 16), __uint_as_float(u.w & 0xffff0000u)};
    }

    // layer 1: xb = leaky(W1 xa + b1)
    #pragma unroll
    for (int i = 0; i < DA; ++i) {
        v2f acc = (v2f){b1[i], 0.0f};
        #pragma unroll
        for (int j2 = 0; j2 < 16; ++j2) pk_fma_s(acc, W1v[i*16 + j2], xa[j2]);
        float h = acc.x + acc.y;
        h = (h >= 0.0f) ? h : 0.1f * h;
        if (i & 1) xb[i >> 1].y = h; else xb[i >> 1].x = h;
    }
    // layer 2: xa = leaky(W2 xb + b2)
    #pragma unroll
    for (int i = 0; i < DA; ++i) {
        v2f acc = (v2f){b2[i], 0.0f};
        #pragma unroll
        for (int j2 = 0; j2 < 16; ++j2) pk_fma_s(acc, W2v[i*16 + j2], xb[j2]);
        float h = acc.x + acc.y;
        h = (h >= 0.0f) ? h : 0.1f * h;
        if (i & 1) xa[i >> 1].y = h; else xa[i >> 1].x = h;
    }
    // layer 3: xb = W3 xa
    #pragma unroll
    for (int i = 0; i < DA; ++i) {
        v2f acc = (v2f){0.0f, 0.0f};
        #pragma unroll
        for (int j2 = 0; j2 < 16; ++j2) pk_fma_s(acc, W3v[i*16 + j2], xa[j2]);
        const float h = acc.x + acc.y;
        if (i & 1) xb[i >> 1].y = h; else xb[i >> 1].x = h;
    }

    rvn_lds[wv][lane] = make_float4(vx, vy, vz, __int_as_float(node));

    // ---- two-pass transpose + serial segmented reduce ----
    const int p = lane >> 5;
    const int i = lane & 31;

    if (lane < 32) {
        float* rrow = rad_lds[wv][lane];
        #pragma unroll
        for (int q = 0; q < 8; ++q) {
            *(float4*)&rrow[q*4] = make_float4(xb[2*q].x, xb[2*q].y, xb[2*q+1].x, xb[2*q+1].y);
        }
    }
    wsync();

    float accA = 0.0f, a0 = 0.0f, a1 = 0.0f, a2 = 0.0f;
    int cur = __float_as_int(rvn_lds[wv][0].w);

    #pragma unroll 4
    for (int l = 0; l < 32; ++l) {
        const float4 rvn = rvn_lds[wv][l];          // uniform b128 broadcast
        const int nd = __float_as_int(rvn.w);       // wave-uniform
        const float rd = rad_lds[wv][l][i];
        if (nd != cur) {                            // wave-uniform branch
            if (p == 0) {
                atomicAdd(&A_a[cur*DA + i], accA);
                atomicAdd(&out_v[(cur*DA + i)*3 + 0], a0);
            } else {
                atomicAdd(&out_v[(cur*DA + i)*3 + 1], a1);
                atomicAdd(&out_v[(cur*DA + i)*3 + 2], a2);
            }
            accA = a0 = a1 = a2 = 0.0f;
            cur = nd;
        }
        accA += rd;
        a0 += rd * rvn.x;
        a1 += rd * rvn.y;
        a2 += rd * rvn.z;
    }
    wsync();   // pass-1 reads retired before rows are overwritten

    if (lane >= 32) {
        float* rrow = rad_lds[wv][lane - 32];
        #pragma unroll
        for (int q = 0; q < 8; ++q) {
            *(float4*)&rrow[q*4] = make_float4(xb[2*q].x, xb[2*q].y, xb[2*q+1].x, xb[2*q+1].y);
        }
    }
    wsync();

    #pragma unroll 4
    for (int l = 32; l < 64; ++l) {
        const float4 rvn = rvn_lds[wv][l];
        const int nd = __float_as_int(rvn.w);
        const float rd = rad_lds[wv][l - 32][i];
        if (nd != cur) {
            if (p == 0) {
                atomicAdd(&A_a[cur*DA + i], accA);
                atomicAdd(&out_v[(cur*DA + i)*3 + 0], a0);
            } else {
                atomicAdd(&out_v[(cur*DA + i)*3 + 1], a1);
                atomicAdd(&out_v[(cur*DA + i)*3 + 2], a2);
            }
            accA = a0 = a1 = a2 = 0.0f;
            cur = nd;
        }
        accA += rd;
        a0 += rd * rvn.x;
        a1 += rd * rvn.y;
        a2 += rd * rvn.z;
    }
    if (p == 0) {
        atomicAdd(&A_a[cur*DA + i], accA);
        atomicAdd(&out_v[(cur*DA + i)*3 + 0], a0);
    } else {
        atomicAdd(&out_v[(cur*DA + i)*3 + 1], a1);
        atomicAdd(&out_v[(cur*DA + i)*3 + 2], a2);
    }
}

// ---------------- phase B: out_v[n][v][d] = sum_a Wv[v][a] * A_v[n][a][d], in place ----------------

__global__ __launch_bounds__(256) void dt_node(
    const float* __restrict__ Wv,
    float* Av_out)   // aliased read+write, deliberately NOT restrict
{
    __shared__ float sWv[DA*DA];
    for (int i = threadIdx.x; i < DA*DA; i += 256) sWv[i] = Wv[i];
    __syncthreads();

    const int t = blockIdx.x * 256 + threadIdx.x;   // grid exactly NN*32/256
    const int n = t >> 5;
    const int v = t & 31;

    const float* av = Av_out + (size_t)n * (DA*3);
    float o0 = 0.0f, o1 = 0.0f, o2 = 0.0f;
    #pragma unroll
    for (int a = 0; a < DA; ++a) {
        const float w = sWv[v*DA + a];
        o0 += w * av[a*3 + 0];
        o1 += w * av[a*3 + 1];
        o2 += w * av[a*3 + 2];
    }
    __syncthreads();   // all loads of this block's nodes complete before any store
    float* o = Av_out + (size_t)n * (DA*3) + v*3;
    o[0] = o0; o[1] = o1; o[2] = o2;
}

// ---------------- legacy path (used only if ws too small for the new path) ----------------

__global__ __launch_bounds__(256) void k_scan_legacy(const int* __restrict__ counts,
                                                     int* __restrict__ offsets) {
    __shared__ int part[256];
    const int CH = (NN + 255) / 256;
    const int t = threadIdx.x;
    const int base = t * CH;
    int s = 0;
    for (int k = 0; k < CH; ++k) { const int idx = base + k; if (idx < NN) s += counts[idx]; }
    part[t] = s;
    __syncthreads();
    if (t == 0) {
        int run = 0;
        for (int k = 0; k < 256; ++k) { const int v = part[k]; part[k] = run; run += v; }
    }
    __syncthreads();
    int run = part[t];
    for (int k = 0; k < CH; ++k) {
        const int idx = base + k;
        if (idx < NN) { offsets[idx] = run; run += counts[idx]; }
    }
    if (t == 255) offsets[NN] = run;
}

__global__ __launch_bounds__(256) void k_scatter_legacy(const int* __restrict__ src,
                                                        const int* __restrict__ offsets,
                                                        const int* __restrict__ rank,
                                                        int* __restrict__ edge_ids) {
    const int e = blockIdx.x * 256 + threadIdx.x;
    edge_ids[offsets[src[e]] + rank[e]] = e;
}

__global__ __launch_bounds__(256, 2) void dt_window_legacy(
    const float* __restrict__ r_ij,
    const float* __restrict__ res_emb,
    const int*   __restrict__ src,
    const int*   __restrict__ dst,
    const int*   __restrict__ edge_ids,
    const float* __restrict__ W1, const float* __restrict__ b1,
    const float* __restrict__ W2, const float* __restrict__ b2,
    const float* __restrict__ W3,
    float* __restrict__ A_a,
    float* __restrict__ out_v)
{
    __shared__ float  rad_lds[4][32][36];
    __shared__ float4 rvn_lds[4][64];

    const int tid  = threadIdx.x;
    const int wv   = tid >> 6;
    const int lane = tid & 63;
    const int slot = blockIdx.x * 256 + tid;

    const int eid  = edge_ids[slot];
    const int node = src[eid];

    const float rx = r_ij[(size_t)eid*3 + 0];
    const float ry = r_ij[(size_t)eid*3 + 1];
    const float rz = r_ij[(size_t)eid*3 + 2];
    const float dist = sqrtf(rx*rx + ry*ry + rz*rz);

    float xa[DA], xb[DA];
    #pragma unroll
    for (int m = 0; m < 8; ++m) {
        float sph, cph;
        __sincosf(PI_R0 * (float)(m + 1) * dist, &sph, &cph);
        xa[2*m] = cph; xa[2*m+1] = cph;
        xa[16+2*m] = sph; xa[16+2*m+1] = sph;
    }
    const float4* er = (const float4*)(res_emb + (size_t)dst[eid] * DA);
    #pragma unroll
    for (int q = 0; q < 8; ++q) {
        const float4 v = er[q];
        xa[q*4+0] += v.x; xa[q*4+1] += v.y; xa[q*4+2] += v.z; xa[q*4+3] += v.w;
    }
    #pragma unroll
    for (int i = 0; i < DA; ++i) {
        float acc = b1[i];
        #pragma unroll
        for (int j = 0; j < DA; ++j) acc += W1[i*DA + j] * xa[j];
        xb[i] = (acc >= 0.0f) ? acc : 0.1f * acc;
    }
    #pragma unroll
    for (int i = 0; i < DA; ++i) {
        float acc = b2[i];
        #pragma unroll
        for (int j = 0; j < DA; ++j) acc += W2[i*DA + j] * xb[j];
        xa[i] = (acc >= 0.0f) ? acc : 0.1f * acc;
    }
    #pragma unroll
    for (int i = 0; i < DA; ++i) {
        float acc = 0.0f;
        #pragma unroll
        for (int j = 0; j < DA; ++j) acc += W3[i*DA + j] * xa[j];
        xb[i] = acc;
    }

    const float qx = rx*1.4f, qy = ry*1.4f, qz = rz*1.4f;
    const float nq = sqrtf(qx*qx + qy*qy + qz*qz);
    const float e2 = __expf(2.0f * nq);
    const float sc = (nq > 0.0f)
        ? (e2 - 1.0f) * __builtin_amdgcn_rcpf((e2 + 1.0f) * nq)
        : 0.0f;

    rvn_lds[wv][lane] = make_float4(qx*sc, qy*sc, qz*sc, __int_as_float(node));

    const int p = lane >> 5;
    const int i = lane & 31;

    if (lane < 32) {
        float* rrow = rad_lds[wv][lane];
        #pragma unroll
        for (int q = 0; q < 8; ++q)
            *(float4*)&rrow[q*4] = make_float4(xb[q*4+0], xb[q*4+1], xb[q*4+2], xb[q*4+3]);
    }
    wsync();

    float accA = 0.0f, a0 = 0.0f, a1 = 0.0f, a2 = 0.0f;
    int cur = __float_as_int(rvn_lds[wv][0].w);

    #pragma unroll 4
    for (int l = 0; l < 32; ++l) {
        const float4 rvn = rvn_lds[wv][l];
        const int nd = __float_as_int(rvn.w);
        const float rd = rad_lds[wv][l][i];
        if (nd != cur) {
            if (p == 0) {
                atomicAdd(&A_a[cur*DA + i], accA);
                atomicAdd(&out_v[(cur*DA + i)*3 + 0], a0);
            } else {
                atomicAdd(&out_v[(cur*DA + i)*3 + 1], a1);
                atomicAdd(&out_v[(cur*DA + i)*3 + 2], a2);
            }
            accA = a0 = a1 = a2 = 0.0f;
            cur = nd;
        }
        accA += rd; a0 += rd*rvn.x; a1 += rd*rvn.y; a2 += rd*rvn.z;
    }
    wsync();
    if (lane >= 32) {
        float* rrow = rad_lds[wv][lane - 32];
        #pragma unroll
        for (int q = 0; q < 8; ++q)
            *(float4*)&rrow[q*4] = make_float4(xb[q*4+0], xb[q*4+1], xb[q*4+2], xb[q*4+3]);
    }
    wsync();
    #pragma unroll 4
    for (int l = 32; l < 64; ++l) {
        const float4 rvn = rvn_lds[wv][l];
        const int nd = __float_as_int(rvn.w);
        const float rd = rad_lds[wv][l - 32][i];
        if (nd != cur) {
            if (p == 0) {
                atomicAdd(&A_a[cur*DA + i], accA);
                atomicAdd(&out_v[(cur*DA + i)*3 + 0], a0);
            } else {
                atomicAdd(&out_v[(cur*DA + i)*3 + 1], a1);
                atomicAdd(&out_v[(cur*DA + i)*3 + 2], a2);
            }
            accA = a0 = a1 = a2 = 0.0f;
            cur = nd;
        }
        accA += rd; a0 += rd*rvn.x; a1 += rd*rvn.y; a2 += rd*rvn.z;
    }
    if (p == 0) {
        atomicAdd(&A_a[cur*DA + i], accA);
        atomicAdd(&out_v[(cur*DA + i)*3 + 0], a0);
    } else {
        atomicAdd(&out_v[(cur*DA + i)*3 + 1], a1);
        atomicAdd(&out_v[(cur*DA + i)*3 + 2], a2);
    }
}

// ---------------- launch ----------------

extern "C" void kernel_launch(void* const* d_in, const int* in_sizes, int n_in,
                              void* d_out, int out_size, void* d_ws, size_t ws_size,
                              hipStream_t stream) {
    const float* r_ij    = (const float*)d_in[0];
    const float* res_emb = (const float*)d_in[1];
    const int*   src     = (const int*)d_in[2];
    const int*   dst     = (const int*)d_in[3];
    const float* W1      = (const float*)d_in[4];
    const float* b1      = (const float*)d_in[5];
    const float* W2      = (const float*)d_in[6];
    const float* b2      = (const float*)d_in[7];
    const float* W3      = (const float*)d_in[8];
    const float* Wv      = (const float*)d_in[9];

    float* A_a   = (float*)d_out;                    // [NN][32]
    float* out_v = (float*)d_out + (size_t)NN * DA;  // [NN][32][3]

    // new-path ws: rec[NE]u32x4 | emb16[NN*16] | counts[NN] | offsets[NN+1] | rank[NE] | bsum | bbase
    const size_t need_new = ((size_t)NE*4 + (size_t)NN*16 + NN + NN + 1 + NE + 256 + 256) * sizeof(int);
    // legacy ws: counts | offsets | rank | edge_ids
    const size_t need_leg = ((size_t)NN + NN + 1 + NE + NE) * sizeof(int);

    // output is accumulated into -> must be zeroed every call
    hipMemsetAsync(d_out, 0, (size_t)out_size * sizeof(float), stream);

    if (ws_size >= need_new) {
        uint4*    rec     = (uint4*)d_ws;
        unsigned* emb16   = (unsigned*)(rec + NE);
        int*      counts  = (int*)(emb16 + (size_t)NN*16);
        int*      offsets = counts + NN;
        int*      rank    = offsets + NN + 1;
        int*      bsum    = rank + NE;
        int*      bbase   = bsum + 256;

        hipMemsetAsync(counts, 0, (size_t)NN * sizeof(int), stream);
        k_hist  <<<NE / 256, 256, 0, stream>>>(src, counts, rank);
        k_scanA <<<SCAN_BLOCKS, 256, 0, stream>>>(counts, bsum);
        k_scanB <<<1, 256, 0, stream>>>(bsum, bbase);
        k_scanC <<<SCAN_BLOCKS, 256, 0, stream>>>(counts, bbase, offsets);
        k_embcvt<<<(NN*16) / 256, 256, 0, stream>>>(res_emb, emb16);
        k_prep  <<<NE / 256, 256, 0, stream>>>(r_ij, src, dst, offsets, rank, rec);
        dt_window<<<NE / 256, 256, 0, stream>>>(rec, emb16,
                                                W1, b1, W2, b2, W3, A_a, out_v);
        dt_node <<<(NN * DA) / 256, 256, 0, stream>>>(Wv, out_v);
    } else if (ws_size >= need_leg) {
        int* counts   = (int*)d_ws;
        int* offsets  = counts + NN;
        int* rank     = offsets + NN + 1;
        int* edge_ids = rank + NE;

        hipMemsetAsync(counts, 0, (size_t)NN * sizeof(int), stream);
        k_hist          <<<NE / 256, 256, 0, stream>>>(src, counts, rank);
        k_scan_legacy   <<<1, 256, 0, stream>>>(counts, offsets);
        k_scatter_legacy<<<NE / 256, 256, 0, stream>>>(src, offsets, rank, edge_ids);
        dt_window_legacy<<<NE / 256, 256, 0, stream>>>(r_ij, res_emb, src, dst, edge_ids,
                                                       W1, b1, W2, b2, W3, A_a, out_v);
        dt_node         <<<(NN * DA) / 256, 256, 0, stream>>>(Wv, out_v);
    }
}

// Round 10
// 248.744 us; speedup vs baseline: 2.9433x; 1.2734x over previous
//
#include <hip/hip_runtime.h>
#include <math.h>

// DisplacementTensors: per-edge radial-MLP + segment-sum to nodes + per-node linear map.
// N_NODES=50000, N_EDGES=1600000, DIM_A=DIM_V=32, R0=5, LEAK=0.1
//
// Round 10: r9 showed the limiter is the scalar weight stream (12KB s_load
// re-read per window, lgkmcnt stalls). The MLP is matmul-shaped -> MFMA:
// per wave-window H^T = W X^T, 4x mfma_f32_32x32x16_bf16 per layer (12 total)
// replace 1536 pk_fma + the scalar stream. K-relabeling freedom (contraction
// invariant under consistent A/B slot->k labeling) means only the verified
// facts are assumed: A row=lane&31, B col=lane&31, D col=lane&31,
// row=(reg&3)+8*(reg>>2)+4*(lane>>5). With labeling k(g,j)=4g+(j&3)+8(j>>2),
// layer L's D regs ARE layer L+1's B frag (register-local chaining; just
// leaky+cvt_pk between layers). W frags loaded once (24 VGPR). One LDS
// round-trip builds the first-layer B frags; layer-3 D is written back to the
// same buffer for the (unchanged) segmented reduce + atomic flush.
//
// d_out layout: A_a [50000*32] floats, then out_v [50000*32*3] floats.
// ws (new path): rec u32[NE*4] | emb16 u32[NN*16] | counts[NN] |
//                offsets[NN+1] | rank[NE] | bsum[256] | bbase[256]

#define NN 50000
#define NE 1600000
#define DA 32
#define PI_R0 0.62831853071795864769f  // pi / 5
#define SCAN_BLOCKS 196                // ceil(NN/256)

typedef float v2f __attribute__((ext_vector_type(2)));
typedef short bf16x8 __attribute__((ext_vector_type(8)));   // 8 bf16 = 4 VGPRs
typedef float f32x16 __attribute__((ext_vector_type(16)));  // MFMA C/D

union frag_u { unsigned u[4]; bf16x8 v; };

__device__ __forceinline__ void wsync() {
    // intra-wave LDS handoff: wave is lockstep; drain the DS queue.
    asm volatile("s_waitcnt lgkmcnt(0)" ::: "memory");
}

__device__ __forceinline__ unsigned cvt_pk(float lo, float hi) {
    unsigned r;
    asm("v_cvt_pk_bf16_f32 %0, %1, %2" : "=v"(r) : "v"(lo), "v"(hi));
    return r;   // lo -> low 16, hi -> high 16
}

__device__ __forceinline__ float leaky(float x) {
    return fmaxf(x, 0.0f) + 0.1f * fminf(x, 0.0f);
}

// round-to-nearest-ish bf16 (add half-ulp then truncate)
__device__ __forceinline__ unsigned bf_hi(float x) {
    return (__float_as_uint(x) + 0x8000u) >> 16;
}
__device__ __forceinline__ unsigned bf_pack2(float lo, float hi) {
    return bf_hi(lo) | ((__float_as_uint(hi) + 0x8000u) & 0xffff0000u);
}

// ---------------- CSR build ----------------

__global__ __launch_bounds__(256) void k_hist(const int* __restrict__ src,
                                              int* __restrict__ counts,
                                              int* __restrict__ rank) {
    const int e = blockIdx.x * 256 + threadIdx.x;   // grid exactly NE/256
    rank[e] = atomicAdd(&counts[src[e]], 1);
}

__global__ __launch_bounds__(256) void k_scanA(const int* __restrict__ counts,
                                               int* __restrict__ bsum) {
    __shared__ int red[256];
    const int t = threadIdx.x;
    const int idx = blockIdx.x * 256 + t;
    red[t] = (idx < NN) ? counts[idx] : 0;
    __syncthreads();
    #pragma unroll
    for (int off = 128; off > 0; off >>= 1) {
        if (t < off) red[t] += red[t + off];
        __syncthreads();
    }
    if (t == 0) bsum[blockIdx.x] = red[0];
}

__global__ __launch_bounds__(256) void k_scanB(const int* __restrict__ bsum,
                                               int* __restrict__ bbase) {
    __shared__ int s[256];
    const int t = threadIdx.x;
    const int v = (t < SCAN_BLOCKS) ? bsum[t] : 0;
    s[t] = v;
    __syncthreads();
    #pragma unroll
    for (int off = 1; off < 256; off <<= 1) {
        const int x = s[t] + ((t >= off) ? s[t - off] : 0);
        __syncthreads();
        s[t] = x;
        __syncthreads();
    }
    if (t < SCAN_BLOCKS) bbase[t] = s[t] - v;   // exclusive
}

__global__ __launch_bounds__(256) void k_scanC(const int* __restrict__ counts,
                                               const int* __restrict__ bbase,
                                               int* __restrict__ offsets) {
    __shared__ int s[256];
    const int t = threadIdx.x;
    const int idx = blockIdx.x * 256 + t;
    const int v = (idx < NN) ? counts[idx] : 0;
    s[t] = v;
    __syncthreads();
    #pragma unroll
    for (int off = 1; off < 256; off <<= 1) {
        const int x = s[t] + ((t >= off) ? s[t - off] : 0);
        __syncthreads();
        s[t] = x;
        __syncthreads();
    }
    const int excl = s[t] - v + bbase[blockIdx.x];
    if (idx < NN) offsets[idx] = excl;
    if (idx == NN - 1) offsets[NN] = excl + v;   // == NE
}

// scatter + per-edge precompute: sequential reads, random fire-and-forget writes.
// rec = {dist f32, vx|vy bf16x2, vz bf16, src u16 | dst u16 << 16}
__global__ __launch_bounds__(256) void k_prep(
    const float* __restrict__ r_ij,
    const int*   __restrict__ src,
    const int*   __restrict__ dst,
    const int*   __restrict__ offsets,
    const int*   __restrict__ rank,
    uint4* __restrict__ rec)
{
    const int e = blockIdx.x * 256 + threadIdx.x;   // grid exactly NE/256
    const int s = src[e];
    const int slot = offsets[s] + rank[e];

    const float rx = r_ij[(size_t)e*3 + 0];
    const float ry = r_ij[(size_t)e*3 + 1];
    const float rz = r_ij[(size_t)e*3 + 2];
    const float dist = sqrtf(rx*rx + ry*ry + rz*rz);

    const float nq = 1.4f * dist;
    const float e2 = __expf(2.0f * nq);
    const float sc14 = (nq > 0.0f)
        ? 1.4f * (e2 - 1.0f) * __builtin_amdgcn_rcpf((e2 + 1.0f) * nq)
        : 0.0f;

    uint4 r;
    r.x = __float_as_uint(dist);
    r.y = bf_pack2(rx * sc14, ry * sc14);
    r.z = bf_hi(rz * sc14);
    r.w = (unsigned)s | ((unsigned)dst[e] << 16);   // both < 65536
    rec[slot] = r;
}

// res_emb f32 [NN][32] -> packed bf16 u32 [NN][16]
__global__ __launch_bounds__(256) void k_embcvt(const float* __restrict__ emb,
                                                unsigned* __restrict__ emb16) {
    const int t = blockIdx.x * 256 + threadIdx.x;   // grid exactly NN*16/256 = 3125
    emb16[t] = bf_pack2(emb[2*t], emb[2*t + 1]);
}

// ---------------- phase A: MFMA MLP over CSR windows + segmented flush ----------------
// block = 256 = 4 waves; wave owns 64 consecutive CSR slots (one per lane).
// H^T = W X^T per layer: A = W (rows = outputs, lane&31), B = X^T (cols =
// edges, lane&31), 2 N-tiles x 2 K-halves = 4 MFMA/layer. k-slot labeling
// k(g,j) = 4g + (j&3) + 8*(j>>2) (+16 for the 2nd MFMA); D row formula
// (reg&3)+8*(reg>>2)+4g then makes D regs == next layer's B slots.

__global__ __launch_bounds__(256, 2) void dt_window(
    const uint4*    __restrict__ rec,
    const unsigned* __restrict__ emb16,
    const float* __restrict__ W1, const float* __restrict__ b1,
    const float* __restrict__ W2, const float* __restrict__ b2,
    const float* __restrict__ W3,
    float* __restrict__ A_a,    // [NN][32]  (accumulates, pre-zeroed)
    float* __restrict__ out_v)  // [NN][32][3] (accumulates raw A_v, pre-zeroed)
{
    __shared__ float  xrad[4][64][36];   // [wave][edge][...]: first 16 u32 = x bf16 pairs, later 32 f32 = rad
    __shared__ float4 rvn_lds[4][64];    // [wave][slot] = (vx, vy, vz, bits(node))

    const int tid  = threadIdx.x;
    const int wv   = tid >> 6;
    const int lane = tid & 63;
    const int g    = lane >> 5;          // k-group / lane half
    const int m    = lane & 31;          // row (A) / col (B) within tile
    const int slot = blockIdx.x * 256 + tid;   // grid exactly NE/256

    // ---- W fragments, loaded once: wf[layer][kt], A-slot j holds W[m][k(g,j)+16kt] ----
    frag_u wf1[2], wf2[2], wf3[2];
    #pragma unroll
    for (int kt = 0; kt < 2; ++kt) {
        const float4 a1 = *(const float4*)&W1[m*DA + 16*kt + 4*g];
        const float4 c1 = *(const float4*)&W1[m*DA + 16*kt + 8 + 4*g];
        wf1[kt].u[0] = cvt_pk(a1.x, a1.y); wf1[kt].u[1] = cvt_pk(a1.z, a1.w);
        wf1[kt].u[2] = cvt_pk(c1.x, c1.y); wf1[kt].u[3] = cvt_pk(c1.z, c1.w);
        const float4 a2 = *(const float4*)&W2[m*DA + 16*kt + 4*g];
        const float4 c2 = *(const float4*)&W2[m*DA + 16*kt + 8 + 4*g];
        wf2[kt].u[0] = cvt_pk(a2.x, a2.y); wf2[kt].u[1] = cvt_pk(a2.z, a2.w);
        wf2[kt].u[2] = cvt_pk(c2.x, c2.y); wf2[kt].u[3] = cvt_pk(c2.z, c2.w);
        const float4 a3 = *(const float4*)&W3[m*DA + 16*kt + 4*g];
        const float4 c3 = *(const float4*)&W3[m*DA + 16*kt + 8 + 4*g];
        wf3[kt].u[0] = cvt_pk(a3.x, a3.y); wf3[kt].u[1] = cvt_pk(a3.z, a3.w);
        wf3[kt].u[2] = cvt_pk(c3.x, c3.y); wf3[kt].u[3] = cvt_pk(c3.z, c3.w);
    }

    // bias per D-reg r: dim d(r,g) = (r&3) + 8*(r>>2) + 4g
    const float4 b1q0 = *(const float4*)&b1[4*g];
    const float4 b1q1 = *(const float4*)&b1[8 + 4*g];
    const float4 b1q2 = *(const float4*)&b1[16 + 4*g];
    const float4 b1q3 = *(const float4*)&b1[24 + 4*g];
    const float4 b2q0 = *(const float4*)&b2[4*g];
    const float4 b2q1 = *(const float4*)&b2[8 + 4*g];
    const float4 b2q2 = *(const float4*)&b2[16 + 4*g];
    const float4 b2q3 = *(const float4*)&b2[24 + 4*g];

    // ---- per-edge input: radial encode + bf16 emb gather ----
    const uint4 rc = rec[slot];                // sequential b128
    const float dist = __uint_as_float(rc.x);
    const float vx = __uint_as_float(rc.y << 16);
    const float vy = __uint_as_float(rc.y & 0xffff0000u);
    const float vz = __uint_as_float(rc.z << 16);
    const int  node = (int)(rc.w & 0xffffu);
    const int  dn   = (int)(rc.w >> 16);

    v2f xa[16];
    #pragma unroll
    for (int mm = 0; mm < 8; ++mm) {
        float sph, cph;
        __sincosf(PI_R0 * (float)(mm + 1) * dist, &sph, &cph);
        xa[mm]     = (v2f){cph, cph};
        xa[8 + mm] = (v2f){sph, sph};
    }
    const uint4* ep = (const uint4*)(emb16 + (size_t)dn * 16);
    #pragma unroll
    for (int q = 0; q < 4; ++q) {
        const uint4 u = ep[q];
        xa[q*4 + 0] += (v2f){__uint_as_float(u.x << 16), __uint_as_float(u.x & 0xffff0000u)};
        xa[q*4 + 1] += (v2f){__uint_as_float(u.y << 16), __uint_as_float(u.y & 0xffff0000u)};
        xa[q*4 + 2] += (v2f){__uint_as_float(u.z << 16), __uint_as_float(u.z & 0xffff0000u)};
        xa[q*4 + 3] += (v2f){__uint_as_float(u.w << 16), __uint_as_float(u.w & 0xffff0000u)};
    }

    rvn_lds[wv][lane] = make_float4(vx, vy, vz, __int_as_float(node));

    // pack x to bf16 pairs and stash: lane's edge row = lane
    {
        unsigned* xr = (unsigned*)&xrad[wv][lane][0];
        uint4 w0, w1_, w2_, w3_;
        w0.x  = cvt_pk(xa[0].x,  xa[0].y);  w0.y  = cvt_pk(xa[1].x,  xa[1].y);
        w0.z  = cvt_pk(xa[2].x,  xa[2].y);  w0.w  = cvt_pk(xa[3].x,  xa[3].y);
        w1_.x = cvt_pk(xa[4].x,  xa[4].y);  w1_.y = cvt_pk(xa[5].x,  xa[5].y);
        w1_.z = cvt_pk(xa[6].x,  xa[6].y);  w1_.w = cvt_pk(xa[7].x,  xa[7].y);
        w2_.x = cvt_pk(xa[8].x,  xa[8].y);  w2_.y = cvt_pk(xa[9].x,  xa[9].y);
        w2_.z = cvt_pk(xa[10].x, xa[10].y); w2_.w = cvt_pk(xa[11].x, xa[11].y);
        w3_.x = cvt_pk(xa[12].x, xa[12].y); w3_.y = cvt_pk(xa[13].x, xa[13].y);
        w3_.z = cvt_pk(xa[14].x, xa[14].y); w3_.w = cvt_pk(xa[15].x, xa[15].y);
        ((uint4*)xr)[0] = w0; ((uint4*)xr)[1] = w1_;
        ((uint4*)xr)[2] = w2_; ((uint4*)xr)[3] = w3_;
    }
    wsync();

    // ---- first-layer B fragments: B-slot j of tile t holds x[edge 32t+m][k(g,j)+16kt] ----
    frag_u xf[2][2];
    #pragma unroll
    for (int t = 0; t < 2; ++t) {
        const unsigned* er = (const unsigned*)&xrad[wv][32*t + m][0];
        #pragma unroll
        for (int kt = 0; kt < 2; ++kt) {
            const uint2 qa = *(const uint2*)&er[8*kt + 2*g];       // dims 16kt+4g..+3
            const uint2 qb = *(const uint2*)&er[8*kt + 4 + 2*g];   // dims 16kt+8+4g..+3
            xf[t][kt].u[0] = qa.x; xf[t][kt].u[1] = qa.y;
            xf[t][kt].u[2] = qb.x; xf[t][kt].u[3] = qb.y;
        }
    }

    // ---- layer 1 ----
    f32x16 acc0, acc1;
    acc0[0]=b1q0.x; acc0[1]=b1q0.y; acc0[2]=b1q0.z; acc0[3]=b1q0.w;
    acc0[4]=b1q1.x; acc0[5]=b1q1.y; acc0[6]=b1q1.z; acc0[7]=b1q1.w;
    acc0[8]=b1q2.x; acc0[9]=b1q2.y; acc0[10]=b1q2.z; acc0[11]=b1q2.w;
    acc0[12]=b1q3.x; acc0[13]=b1q3.y; acc0[14]=b1q3.z; acc0[15]=b1q3.w;
    acc1 = acc0;
    acc0 = __builtin_amdgcn_mfma_f32_32x32x16_bf16(wf1[0].v, xf[0][0].v, acc0, 0, 0, 0);
    acc0 = __builtin_amdgcn_mfma_f32_32x32x16_bf16(wf1[1].v, xf[0][1].v, acc0, 0, 0, 0);
    acc1 = __builtin_amdgcn_mfma_f32_32x32x16_bf16(wf1[0].v, xf[1][0].v, acc1, 0, 0, 0);
    acc1 = __builtin_amdgcn_mfma_f32_32x32x16_bf16(wf1[1].v, xf[1][1].v, acc1, 0, 0, 0);

    // leaky + repack: D regs -> next-layer B frags (register-local)
    frag_u hf[2][2];
    #pragma unroll
    for (int t = 0; t < 2; ++t) {
        const f32x16 a = t ? acc1 : acc0;
        float h[16];
        #pragma unroll
        for (int r = 0; r < 16; ++r) h[r] = leaky(a[r]);
        hf[t][0].u[0] = cvt_pk(h[0], h[1]);   hf[t][0].u[1] = cvt_pk(h[2], h[3]);
        hf[t][0].u[2] = cvt_pk(h[4], h[5]);   hf[t][0].u[3] = cvt_pk(h[6], h[7]);
        hf[t][1].u[0] = cvt_pk(h[8], h[9]);   hf[t][1].u[1] = cvt_pk(h[10], h[11]);
        hf[t][1].u[2] = cvt_pk(h[12], h[13]); hf[t][1].u[3] = cvt_pk(h[14], h[15]);
    }

    // ---- layer 2 ----
    f32x16 c0, c1;
    c0[0]=b2q0.x; c0[1]=b2q0.y; c0[2]=b2q0.z; c0[3]=b2q0.w;
    c0[4]=b2q1.x; c0[5]=b2q1.y; c0[6]=b2q1.z; c0[7]=b2q1.w;
    c0[8]=b2q2.x; c0[9]=b2q2.y; c0[10]=b2q2.z; c0[11]=b2q2.w;
    c0[12]=b2q3.x; c0[13]=b2q3.y; c0[14]=b2q3.z; c0[15]=b2q3.w;
    c1 = c0;
    c0 = __builtin_amdgcn_mfma_f32_32x32x16_bf16(wf2[0].v, hf[0][0].v, c0, 0, 0, 0);
    c0 = __builtin_amdgcn_mfma_f32_32x32x16_bf16(wf2[1].v, hf[0][1].v, c0, 0, 0, 0);
    c1 = __builtin_amdgcn_mfma_f32_32x32x16_bf16(wf2[0].v, hf[1][0].v, c1, 0, 0, 0);
    c1 = __builtin_amdgcn_mfma_f32_32x32x16_bf16(wf2[1].v, hf[1][1].v, c1, 0, 0, 0);

    frag_u gf[2][2];
    #pragma unroll
    for (int t = 0; t < 2; ++t) {
        const f32x16 a = t ? c1 : c0;
        float h[16];
        #pragma unroll
        for (int r = 0; r < 16; ++r) h[r] = leaky(a[r]);
        gf[t][0].u[0] = cvt_pk(h[0], h[1]);   gf[t][0].u[1] = cvt_pk(h[2], h[3]);
        gf[t][0].u[2] = cvt_pk(h[4], h[5]);   gf[t][0].u[3] = cvt_pk(h[6], h[7]);
        gf[t][1].u[0] = cvt_pk(h[8], h[9]);   gf[t][1].u[1] = cvt_pk(h[10], h[11]);
        gf[t][1].u[2] = cvt_pk(h[12], h[13]); gf[t][1].u[3] = cvt_pk(h[14], h[15]);
    }

    // ---- layer 3 (no bias, no activation) ----
    f32x16 r0 = {}, r1 = {};
    r0 = __builtin_amdgcn_mfma_f32_32x32x16_bf16(wf3[0].v, gf[0][0].v, r0, 0, 0, 0);
    r0 = __builtin_amdgcn_mfma_f32_32x32x16_bf16(wf3[1].v, gf[0][1].v, r0, 0, 0, 0);
    r1 = __builtin_amdgcn_mfma_f32_32x32x16_bf16(wf3[0].v, gf[1][0].v, r1, 0, 0, 0);
    r1 = __builtin_amdgcn_mfma_f32_32x32x16_bf16(wf3[1].v, gf[1][1].v, r1, 0, 0, 0);

    // ---- write rad back: lane holds edge 32t+m, dims quads {4g, 8+4g, 16+4g, 24+4g} ----
    #pragma unroll
    for (int t = 0; t < 2; ++t) {
        const f32x16 a = t ? r1 : r0;
        float* rr = &xrad[wv][32*t + m][0];
        *(float4*)&rr[4*g]      = make_float4(a[0],  a[1],  a[2],  a[3]);
        *(float4*)&rr[8 + 4*g]  = make_float4(a[4],  a[5],  a[6],  a[7]);
        *(float4*)&rr[16 + 4*g] = make_float4(a[8],  a[9],  a[10], a[11]);
        *(float4*)&rr[24 + 4*g] = make_float4(a[12], a[13], a[14], a[15]);
    }
    wsync();

    // ---- serial segmented reduce over the wave's 64 slots (unchanged scheme) ----
    const int p = lane >> 5;
    const int i = lane & 31;

    float accA = 0.0f, a0 = 0.0f, a1 = 0.0f, a2 = 0.0f;
    int cur = __float_as_int(rvn_lds[wv][0].w);

    #pragma unroll 4
    for (int l = 0; l < 64; ++l) {
        const float4 rvn = rvn_lds[wv][l];          // uniform b128 broadcast
        const int nd = __float_as_int(rvn.w);       // wave-uniform
        const float rd = xrad[wv][l][i];            // 32 consecutive banks
        if (nd != cur) {                            // wave-uniform branch
            if (p == 0) {
                atomicAdd(&A_a[cur*DA + i], accA);
                atomicAdd(&out_v[(cur*DA + i)*3 + 0], a0);
            } else {
                atomicAdd(&out_v[(cur*DA + i)*3 + 1], a1);
                atomicAdd(&out_v[(cur*DA + i)*3 + 2], a2);
            }
            accA = a0 = a1 = a2 = 0.0f;
            cur = nd;
        }
        accA += rd;
        a0 += rd * rvn.x;
        a1 += rd * rvn.y;
        a2 += rd * rvn.z;
    }
    if (p == 0) {
        atomicAdd(&A_a[cur*DA + i], accA);
        atomicAdd(&out_v[(cur*DA + i)*3 + 0], a0);
    } else {
        atomicAdd(&out_v[(cur*DA + i)*3 + 1], a1);
        atomicAdd(&out_v[(cur*DA + i)*3 + 2], a2);
    }
}

// ---------------- phase B: out_v[n][v][d] = sum_a Wv[v][a] * A_v[n][a][d], in place ----------------

__global__ __launch_bounds__(256) void dt_node(
    const float* __restrict__ Wv,
    float* Av_out)   // aliased read+write, deliberately NOT restrict
{
    __shared__ float sWv[DA*DA];
    for (int i = threadIdx.x; i < DA*DA; i += 256) sWv[i] = Wv[i];
    __syncthreads();

    const int t = blockIdx.x * 256 + threadIdx.x;   // grid exactly NN*32/256
    const int n = t >> 5;
    const int v = t & 31;

    const float* av = Av_out + (size_t)n * (DA*3);
    float o0 = 0.0f, o1 = 0.0f, o2 = 0.0f;
    #pragma unroll
    for (int a = 0; a < DA; ++a) {
        const float w = sWv[v*DA + a];
        o0 += w * av[a*3 + 0];
        o1 += w * av[a*3 + 1];
        o2 += w * av[a*3 + 2];
    }
    __syncthreads();   // all loads of this block's nodes complete before any store
    float* o = Av_out + (size_t)n * (DA*3) + v*3;
    o[0] = o0; o[1] = o1; o[2] = o2;
}

// ---------------- legacy path (used only if ws too small for the new path) ----------------

__global__ __launch_bounds__(256) void k_scan_legacy(const int* __restrict__ counts,
                                                     int* __restrict__ offsets) {
    __shared__ int part[256];
    const int CH = (NN + 255) / 256;
    const int t = threadIdx.x;
    const int base = t * CH;
    int s = 0;
    for (int k = 0; k < CH; ++k) { const int idx = base + k; if (idx < NN) s += counts[idx]; }
    part[t] = s;
    __syncthreads();
    if (t == 0) {
        int run = 0;
        for (int k = 0; k < 256; ++k) { const int v = part[k]; part[k] = run; run += v; }
    }
    __syncthreads();
    int run = part[t];
    for (int k = 0; k < CH; ++k) {
        const int idx = base + k;
        if (idx < NN) { offsets[idx] = run; run += counts[idx]; }
    }
    if (t == 255) offsets[NN] = run;
}

__global__ __launch_bounds__(256) void k_scatter_legacy(const int* __restrict__ src,
                                                        const int* __restrict__ offsets,
                                                        const int* __restrict__ rank,
                                                        int* __restrict__ edge_ids) {
    const int e = blockIdx.x * 256 + threadIdx.x;
    edge_ids[offsets[src[e]] + rank[e]] = e;
}

__global__ __launch_bounds__(256, 2) void dt_window_legacy(
    const float* __restrict__ r_ij,
    const float* __restrict__ res_emb,
    const int*   __restrict__ src,
    const int*   __restrict__ dst,
    const int*   __restrict__ edge_ids,
    const float* __restrict__ W1, const float* __restrict__ b1,
    const float* __restrict__ W2, const float* __restrict__ b2,
    const float* __restrict__ W3,
    float* __restrict__ A_a,
    float* __restrict__ out_v)
{
    __shared__ float  rad_lds[4][32][36];
    __shared__ float4 rvn_lds[4][64];

    const int tid  = threadIdx.x;
    const int wv   = tid >> 6;
    const int lane = tid & 63;
    const int slot = blockIdx.x * 256 + tid;

    const int eid  = edge_ids[slot];
    const int node = src[eid];

    const float rx = r_ij[(size_t)eid*3 + 0];
    const float ry = r_ij[(size_t)eid*3 + 1];
    const float rz = r_ij[(size_t)eid*3 + 2];
    const float dist = sqrtf(rx*rx + ry*ry + rz*rz);

    float xa[DA], xb[DA];
    #pragma unroll
    for (int mm = 0; mm < 8; ++mm) {
        float sph, cph;
        __sincosf(PI_R0 * (float)(mm + 1) * dist, &sph, &cph);
        xa[2*mm] = cph; xa[2*mm+1] = cph;
        xa[16+2*mm] = sph; xa[16+2*mm+1] = sph;
    }
    const float4* er = (const float4*)(res_emb + (size_t)dst[eid] * DA);
    #pragma unroll
    for (int q = 0; q < 8; ++q) {
        const float4 v = er[q];
        xa[q*4+0] += v.x; xa[q*4+1] += v.y; xa[q*4+2] += v.z; xa[q*4+3] += v.w;
    }
    #pragma unroll
    for (int i = 0; i < DA; ++i) {
        float acc = b1[i];
        #pragma unroll
        for (int j = 0; j < DA; ++j) acc += W1[i*DA + j] * xa[j];
        xb[i] = (acc >= 0.0f) ? acc : 0.1f * acc;
    }
    #pragma unroll
    for (int i = 0; i < DA; ++i) {
        float acc = b2[i];
        #pragma unroll
        for (int j = 0; j < DA; ++j) acc += W2[i*DA + j] * xb[j];
        xa[i] = (acc >= 0.0f) ? acc : 0.1f * acc;
    }
    #pragma unroll
    for (int i = 0; i < DA; ++i) {
        float acc = 0.0f;
        #pragma unroll
        for (int j = 0; j < DA; ++j) acc += W3[i*DA + j] * xa[j];
        xb[i] = acc;
    }

    const float qx = rx*1.4f, qy = ry*1.4f, qz = rz*1.4f;
    const float nq = sqrtf(qx*qx + qy*qy + qz*qz);
    const float e2 = __expf(2.0f * nq);
    const float sc = (nq > 0.0f)
        ? (e2 - 1.0f) * __builtin_amdgcn_rcpf((e2 + 1.0f) * nq)
        : 0.0f;

    rvn_lds[wv][lane] = make_float4(qx*sc, qy*sc, qz*sc, __int_as_float(node));

    const int p = lane >> 5;
    const int i = lane & 31;

    if (lane < 32) {
        float* rrow = rad_lds[wv][lane];
        #pragma unroll
        for (int q = 0; q < 8; ++q)
            *(float4*)&rrow[q*4] = make_float4(xb[q*4+0], xb[q*4+1], xb[q*4+2], xb[q*4+3]);
    }
    wsync();

    float accA = 0.0f, a0 = 0.0f, a1 = 0.0f, a2 = 0.0f;
    int cur = __float_as_int(rvn_lds[wv][0].w);

    #pragma unroll 4
    for (int l = 0; l < 32; ++l) {
        const float4 rvn = rvn_lds[wv][l];
        const int nd = __float_as_int(rvn.w);
        const float rd = rad_lds[wv][l][i];
        if (nd != cur) {
            if (p == 0) {
                atomicAdd(&A_a[cur*DA + i], accA);
                atomicAdd(&out_v[(cur*DA + i)*3 + 0], a0);
            } else {
                atomicAdd(&out_v[(cur*DA + i)*3 + 1], a1);
                atomicAdd(&out_v[(cur*DA + i)*3 + 2], a2);
            }
            accA = a0 = a1 = a2 = 0.0f;
            cur = nd;
        }
        accA += rd; a0 += rd*rvn.x; a1 += rd*rvn.y; a2 += rd*rvn.z;
    }
    wsync();
    if (lane >= 32) {
        float* rrow = rad_lds[wv][lane - 32];
        #pragma unroll
        for (int q = 0; q < 8; ++q)
            *(float4*)&rrow[q*4] = make_float4(xb[q*4+0], xb[q*4+1], xb[q*4+2], xb[q*4+3]);
    }
    wsync();
    #pragma unroll 4
    for (int l = 32; l < 64; ++l) {
        const float4 rvn = rvn_lds[wv][l];
        const int nd = __float_as_int(rvn.w);
        const float rd = rad_lds[wv][l - 32][i];
        if (nd != cur) {
            if (p == 0) {
                atomicAdd(&A_a[cur*DA + i], accA);
                atomicAdd(&out_v[(cur*DA + i)*3 + 0], a0);
            } else {
                atomicAdd(&out_v[(cur*DA + i)*3 + 1], a1);
                atomicAdd(&out_v[(cur*DA + i)*3 + 2], a2);
            }
            accA = a0 = a1 = a2 = 0.0f;
            cur = nd;
        }
        accA += rd; a0 += rd*rvn.x; a1 += rd*rvn.y; a2 += rd*rvn.z;
    }
    if (p == 0) {
        atomicAdd(&A_a[cur*DA + i], accA);
        atomicAdd(&out_v[(cur*DA + i)*3 + 0], a0);
    } else {
        atomicAdd(&out_v[(cur*DA + i)*3 + 1], a1);
        atomicAdd(&out_v[(cur*DA + i)*3 + 2], a2);
    }
}

// ---------------- launch ----------------

extern "C" void kernel_launch(void* const* d_in, const int* in_sizes, int n_in,
                              void* d_out, int out_size, void* d_ws, size_t ws_size,
                              hipStream_t stream) {
    const float* r_ij    = (const float*)d_in[0];
    const float* res_emb = (const float*)d_in[1];
    const int*   src     = (const int*)d_in[2];
    const int*   dst     = (const int*)d_in[3];
    const float* W1      = (const float*)d_in[4];
    const float* b1      = (const float*)d_in[5];
    const float* W2      = (const float*)d_in[6];
    const float* b2      = (const float*)d_in[7];
    const float* W3      = (const float*)d_in[8];
    const float* Wv      = (const float*)d_in[9];

    float* A_a   = (float*)d_out;                    // [NN][32]
    float* out_v = (float*)d_out + (size_t)NN * DA;  // [NN][32][3]

    const size_t need_new = ((size_t)NE*4 + (size_t)NN*16 + NN + NN + 1 + NE + 256 + 256) * sizeof(int);
    const size_t need_leg = ((size_t)NN + NN + 1 + NE + NE) * sizeof(int);

    // output is accumulated into -> must be zeroed every call
    hipMemsetAsync(d_out, 0, (size_t)out_size * sizeof(float), stream);

    if (ws_size >= need_new) {
        uint4*    rec     = (uint4*)d_ws;
        unsigned* emb16   = (unsigned*)(rec + NE);
        int*      counts  = (int*)(emb16 + (size_t)NN*16);
        int*      offsets = counts + NN;
        int*      rank    = offsets + NN + 1;
        int*      bsum    = rank + NE;
        int*      bbase   = bsum + 256;

        hipMemsetAsync(counts, 0, (size_t)NN * sizeof(int), stream);
        k_hist  <<<NE / 256, 256, 0, stream>>>(src, counts, rank);
        k_scanA <<<SCAN_BLOCKS, 256, 0, stream>>>(counts, bsum);
        k_scanB <<<1, 256, 0, stream>>>(bsum, bbase);
        k_scanC <<<SCAN_BLOCKS, 256, 0, stream>>>(counts, bbase, offsets);
        k_embcvt<<<(NN*16) / 256, 256, 0, stream>>>(res_emb, emb16);
        k_prep  <<<NE / 256, 256, 0, stream>>>(r_ij, src, dst, offsets, rank, rec);
        dt_window<<<NE / 256, 256, 0, stream>>>(rec, emb16,
                                                W1, b1, W2, b2, W3, A_a, out_v);
        dt_node <<<(NN * DA) / 256, 256, 0, stream>>>(Wv, out_v);
    } else if (ws_size >= need_leg) {
        int* counts   = (int*)d_ws;
        int* offsets  = counts + NN;
        int* rank     = offsets + NN + 1;
        int* edge_ids = rank + NE;

        hipMemsetAsync(counts, 0, (size_t)NN * sizeof(int), stream);
        k_hist          <<<NE / 256, 256, 0, stream>>>(src, counts, rank);
        k_scan_legacy   <<<1, 256, 0, stream>>>(counts, offsets);
        k_scatter_legacy<<<NE / 256, 256, 0, stream>>>(src, offsets, rank, edge_ids);
        dt_window_legacy<<<NE / 256, 256, 0, stream>>>(r_ij, res_emb, src, dst, edge_ids,
                                                       W1, b1, W2, b2, W3, A_a, out_v);
        dt_node         <<<(NN * DA) / 256, 256, 0, stream>>>(Wv, out_v);
    }
}